// Round 7
// baseline (860.163 us; speedup 1.0000x reference)
//
#include <hip/hip_runtime.h>
#include <math.h>

typedef unsigned short u16;
typedef unsigned int u32;

typedef __attribute__((ext_vector_type(8))) short short8;
typedef __attribute__((ext_vector_type(4))) float floatx4;

#define NTILES 16384  // B*N*N/64

__device__ __forceinline__ float bfu(u16 u) { return __uint_as_float(((u32)u) << 16); }
__device__ __forceinline__ u16 f2bfs(float f) {
  u32 x = __float_as_uint(f);
  return (u16)((x + 0x7FFFu + ((x >> 16) & 1u)) >> 16);
}
__device__ __forceinline__ float tanh_fast(float x) {
  float e = __builtin_amdgcn_exp2f(x * 2.885390081777927f);
  return 1.0f - 2.0f * __builtin_amdgcn_rcpf(e + 1.0f);
}

// ---- device-scope arrive+spin barrier (proven R5/R6 fence/atomic pattern) ----
__device__ __forceinline__ void gbar(int* cnt, int target) {
  __threadfence();
  __syncthreads();
  if (threadIdx.x == 0) {
    atomicAdd(cnt, 1);
    while (atomicAdd(cnt, 0) < target) __builtin_amdgcn_s_sleep(2);
  }
  __syncthreads();
  __threadfence();
}

// ------------- edge MLP -> e_sum: R5-exact numerics (fp32 layer-1) ------------
__global__ __launch_bounds__(256) void k_edge(const float* __restrict__ ef,
    const float* __restrict__ w1, const float* __restrict__ b1,
    const float* __restrict__ w2, const float* __restrict__ b2,
    float* __restrict__ es32, u16* __restrict__ es16, int use16) {
  __shared__ __align__(16) short T1[64 * 264];
  __shared__ __align__(16) float EF[8 * 64];
  int t = threadIdx.x;
  int lane = t & 63, w = t >> 6, q = lane >> 4, r = lane & 15;

  for (int u = 0; u < 64; ++u) {
    int flat = u * 256 + t;          // flat = k*64 + n
    int k = flat >> 6, n = flat & 63;
    T1[n * 264 + k] = (short)f2bfs(w2[flat]);
  }
  __syncthreads();
  short8 bfr2[8][4];
#pragma unroll
  for (int s = 0; s < 8; ++s)
#pragma unroll
    for (int nt = 0; nt < 4; ++nt)
      bfr2[s][nt] = *(const short8*)(&T1[(nt * 16 + r) * 264 + s * 32 + q * 8]);
  __syncthreads();

  float w1c[8];
#pragma unroll
  for (int c = 0; c < 8; ++c) w1c[c] = w1[c * 256 + t];
  float b1t = b1[t];
  float b2v[4];
#pragma unroll
  for (int nt = 0; nt < 4; ++nt) b2v[nt] = b2[nt * 16 + r];

  for (int tile = blockIdx.x; tile < NTILES; tile += gridDim.x) {
    {
      int m = t >> 2, c = (t & 3) * 2;
      float2 e2 = *(const float2*)(ef + (size_t)tile * 512 + m * 8 + c);
      EF[c * 64 + m] = e2.x;
      EF[(c + 1) * 64 + m] = e2.y;
    }
    __syncthreads();
    for (int mt = 0; mt < 8; ++mt) {
      float acc[8];
#pragma unroll
      for (int mm = 0; mm < 8; ++mm) acc[mm] = b1t;
#pragma unroll
      for (int c = 0; c < 8; ++c) {
        const float4* ep = (const float4*)&EF[c * 64 + mt * 8];
        float4 ea = ep[0], eb = ep[1];
        float wv = w1c[c];
        acc[0] += ea.x * wv; acc[1] += ea.y * wv; acc[2] += ea.z * wv; acc[3] += ea.w * wv;
        acc[4] += eb.x * wv; acc[5] += eb.y * wv; acc[6] += eb.z * wv; acc[7] += eb.w * wv;
      }
#pragma unroll
      for (int mm = 0; mm < 8; ++mm)
        T1[(mt * 8 + mm) * 264 + t] = (short)f2bfs(tanh_fast(acc[mm]));
    }
    __syncthreads();
    floatx4 acc4[4];
#pragma unroll
    for (int nt = 0; nt < 4; ++nt) acc4[nt] = (floatx4){0.f, 0.f, 0.f, 0.f};
    const short* arow = &T1[(w * 16 + r) * 264];
#pragma unroll
    for (int s = 0; s < 8; ++s) {
      short8 af = *(const short8*)(arow + s * 32 + q * 8);
#pragma unroll
      for (int nt = 0; nt < 4; ++nt)
        acc4[nt] = __builtin_amdgcn_mfma_f32_16x16x32_bf16(af, bfr2[s][nt], acc4[nt], 0, 0, 0);
    }
    float s0 = 0.f, s1 = 0.f, s2 = 0.f, s3 = 0.f;
#pragma unroll
    for (int nt = 0; nt < 4; ++nt) {
      float bb = b2v[nt];
      s0 += tanh_fast(acc4[nt][0] + bb);
      s1 += tanh_fast(acc4[nt][1] + bb);
      s2 += tanh_fast(acc4[nt][2] + bb);
      s3 += tanh_fast(acc4[nt][3] + bb);
    }
#pragma unroll
    for (int off = 1; off < 16; off <<= 1) {
      s0 += __shfl_xor(s0, off, 64);
      s1 += __shfl_xor(s1, off, 64);
      s2 += __shfl_xor(s2, off, 64);
      s3 += __shfl_xor(s3, off, 64);
    }
    if (r == 0) {
      int base = tile * 64 + w * 16 + q * 4;
      if (use16) {
        es16[base] = f2bfs(s0); es16[base + 1] = f2bfs(s1);
        es16[base + 2] = f2bfs(s2); es16[base + 3] = f2bfs(s3);
      } else {
        float4 o; o.x = s0; o.y = s1; o.z = s2; o.w = s3;
        *(float4*)&es32[base] = o;
      }
    }
    __syncthreads();  // REQUIRED: EF restage vs prev-tile reads
  }
}

// ---- k_pre: node embed MLP + gcn_tmp(l=0) + dinv + counter zero --------------
__global__ __launch_bounds__(256) void k_pre(const float* __restrict__ nf,
    const float* __restrict__ w1, const float* __restrict__ b1,
    const float* __restrict__ w2, const float* __restrict__ b2,
    const float* __restrict__ gw, const float* __restrict__ adj,
    float* __restrict__ hid, u16* __restrict__ alls16, float* __restrict__ tmp,
    float* __restrict__ dinv, int* __restrict__ cnt) {
  __shared__ float nfx[4][16];
  __shared__ float t1[4][256];
  __shared__ float nh[4][64];
  int t = threadIdx.x;
  int node0 = blockIdx.x * 4;
  if (blockIdx.x == 0 && t < 16) cnt[t] = 0;
  if (t < 64) nfx[t >> 4][t & 15] = nf[node0 * 16 + t];
  __syncthreads();
  float b1t = b1[t];
  float a0 = b1t, a1 = b1t, a2 = b1t, a3 = b1t;
#pragma unroll
  for (int c = 0; c < 16; ++c) {
    float wv = w1[c * 256 + t];
    a0 += nfx[0][c] * wv; a1 += nfx[1][c] * wv;
    a2 += nfx[2][c] * wv; a3 += nfx[3][c] * wv;
  }
  t1[0][t] = tanh_fast(a0); t1[1][t] = tanh_fast(a1);
  t1[2][t] = tanh_fast(a2); t1[3][t] = tanh_fast(a3);
  __syncthreads();
  int nl = t >> 6, h = t & 63;
  {
    float acc = b2[h];
    for (int c = 0; c < 256; c += 4) {
      float4 xv = *(const float4*)&t1[nl][c];
      acc += xv.x * w2[c * 64 + h] + xv.y * w2[(c + 1) * 64 + h]
           + xv.z * w2[(c + 2) * 64 + h] + xv.w * w2[(c + 3) * 64 + h];
    }
    float v = tanh_fast(acc);
    int node = node0 + nl;
    hid[node * 64 + h] = v;
    alls16[node * 256 + h] = f2bfs(v);
    nh[nl][h] = v;
  }
  __syncthreads();
  {
    float g = 0.f;
    for (int c = 0; c < 64; ++c) g += nh[nl][c] * gw[c * 64 + h];
    tmp[(node0 + nl) * 64 + h] = g;
  }
  {
    int lane = t & 63, row = node0 + (t >> 6);
    float s = 0.f;
#pragma unroll
    for (int u = 0; u < 8; ++u) s += adj[(size_t)row * 512 + u * 64 + lane];
#pragma unroll
    for (int off = 32; off > 0; off >>= 1) s += __shfl_xor(s, off, 64);
    if (lane == 0) dinv[row] = 1.0f / (s + 1.0f);
  }
}

// ---- fp32 VALU adjacency matmul (R5 summation order), 16 rows/block ----------
__device__ __forceinline__ void adj_mm32(const float* __restrict__ Af,
    const u16* __restrict__ A16, int useA16,
    const float* __restrict__ X, const float* __restrict__ vnadd,
    const float* __restrict__ dinv, float* __restrict__ out,
    float* __restrict__ vnpart, float* Al, float* Xt, float* red,
    int b, int it) {
  int t = threadIdx.x;
  int row = t >> 4, cq = t & 15;
  floatx4 acc = (floatx4){0.f, 0.f, 0.f, 0.f};
  for (int jt = 0; jt < 8; ++jt) {
    __syncthreads();
#pragma unroll
    for (int u = 0; u < 4; ++u) {        // A tile 16x64 -> Al[row*65+k]
      int idx = u * 256 + t;
      int rr = idx >> 6, kk = idx & 63;
      size_t ai = ((size_t)(b * 512 + it * 16 + rr)) * 512 + jt * 64 + kk;
      Al[rr * 65 + kk] = useA16 ? bfu(A16[ai]) : Af[ai];
    }
#pragma unroll
    for (int u = 0; u < 16; ++u) {       // X tile 64x64, k-major fp32
      int idx = u * 256 + t;
      int kk = idx >> 6, n = idx & 63;
      float xv = X[(size_t)(b * 512 + jt * 64 + kk) * 64 + n];
      if (vnadd) xv += vnadd[b * 64 + n];
      Xt[kk * 64 + n] = xv;
    }
    __syncthreads();
    const float* ap = &Al[row * 65];
    const float* xp = &Xt[cq * 4];
#pragma unroll 8
    for (int jl = 0; jl < 64; ++jl) {
      float a = ap[jl];
      floatx4 xv = *(const floatx4*)(xp + jl * 64);
      acc[0] += a * xv[0]; acc[1] += a * xv[1];
      acc[2] += a * xv[2]; acc[3] += a * xv[3];
    }
  }
  int grow = b * 512 + it * 16 + row;
  floatx4 o;
  if (dinv) {
    float d = dinv[grow];
#pragma unroll
    for (int i = 0; i < 4; ++i) o[i] = tanh_fast(acc[i] * d);
  } else {
#pragma unroll
    for (int i = 0; i < 4; ++i) o[i] = tanh_fast(acc[i]);
  }
  *(floatx4*)&out[(size_t)grow * 64 + cq * 4] = o;
  if (vnpart) {
    *(floatx4*)&red[row * 64 + cq * 4] = o;
    __syncthreads();
    if (t < 64) {
      float s = 0.f;
#pragma unroll
      for (int rr = 0; rr < 16; ++rr) s += red[rr * 64 + t];
      vnpart[(b * 32 + it) * 64 + t] = s;
    }
  }
}

// ---- one fused layer: adjmm0 -> vn_mlp -> adjmm1 -> comb+gcn (128 blocks) ----
__global__ __launch_bounds__(256) void k_layer(const float* __restrict__ adj,
    const float* __restrict__ es32, const u16* __restrict__ es16, int use16,
    float* hid, float* tmp, float* vn, float* __restrict__ vnpart,
    const float* __restrict__ dinv, int* cnt,
    const float* __restrict__ vw1, const float* __restrict__ vb1,
    const float* __restrict__ vg1, const float* __restrict__ vbe1,
    const float* __restrict__ vw2, const float* __restrict__ vb2,
    const float* __restrict__ vg2, const float* __restrict__ vbe2,
    const float* __restrict__ cw, const float* __restrict__ cb,
    const float* __restrict__ gw_next, u16* __restrict__ alls16,
    int l, int do_gcn) {
  __shared__ __align__(16) float Al[16 * 65];
  __shared__ __align__(16) float Xt[64 * 64];
  __shared__ __align__(16) float red[16 * 64];
  int t = threadIdx.x;
  int blk = blockIdx.x;
  int b = blk >> 5, it = blk & 31;

  // phase A: hidden = tanh(dinv * adj @ tmp) + vn partial col-sums
  adj_mm32(adj, (const u16*)0, 0, tmp, (const float*)0, dinv, hid, vnpart,
           Al, Xt, red, b, it);
  gbar(cnt, 128);
  // vn_mlp on block 0 (scratch aliases Xt; other blocks' LDS is private)
  if (blk == 0) {
    float* x0 = Xt; float* x1 = Xt + 256; float* y1 = Xt + 768; float* x2 = Xt + 1280;
    {
      int bb = t >> 6, h = t & 63;
      float s = 0.f;
      for (int c = 0; c < 32; ++c) s += vnpart[(bb * 32 + c) * 64 + h];
      x0[t] = s * (1.0f / 512.0f);
    }
    __syncthreads();
    for (int rep = 0; rep < 2; ++rep) {
      int idx = rep * 256 + t;
      int bb = idx >> 7, j = idx & 127;
      float a = vb1[l * 128 + j];
      for (int h = 0; h < 64; ++h) a += x0[bb * 64 + h] * vw1[l * 8192 + h * 128 + j];
      x1[idx] = a;
    }
    __syncthreads();
    if (t < 128) {
      int j = t;
      float a = x1[j], bq = x1[128 + j], c = x1[256 + j], d = x1[384 + j];
      float m = 0.25f * (a + bq + c + d);
      float da = a - m, db = bq - m, dc = c - m, dd = d - m;
      float var = 0.25f * (da * da + db * db + dc * dc + dd * dd);
      float sc = vg1[l * 128 + j] / sqrtf(var + 1e-5f);
      float be = vbe1[l * 128 + j];
      y1[j]       = fmaxf(sc * da + be, 0.f);
      y1[128 + j] = fmaxf(sc * db + be, 0.f);
      y1[256 + j] = fmaxf(sc * dc + be, 0.f);
      y1[384 + j] = fmaxf(sc * dd + be, 0.f);
    }
    __syncthreads();
    {
      int bb = t >> 6, k = t & 63;
      float a = vb2[l * 64 + k];
      for (int j = 0; j < 128; ++j) a += y1[bb * 128 + j] * vw2[l * 8192 + j * 64 + k];
      x2[t] = a;
    }
    __syncthreads();
    if (t < 64) {
      int k = t;
      float a = x2[k], bq = x2[64 + k], c = x2[128 + k], d = x2[192 + k];
      float m = 0.25f * (a + bq + c + d);
      float da = a - m, db = bq - m, dc = c - m, dd = d - m;
      float var = 0.25f * (da * da + db * db + dc * dc + dd * dd);
      float sc = vg2[l * 64 + k] / sqrtf(var + 1e-5f);
      float be = vbe2[l * 64 + k];
      vn[k]       = fmaxf(sc * da + be, 0.f);
      vn[64 + k]  = fmaxf(sc * db + be, 0.f);
      vn[128 + k] = fmaxf(sc * dc + be, 0.f);
      vn[192 + k] = fmaxf(sc * dd + be, 0.f);
    }
  }
  gbar(cnt, 256);
  // phase B: gated = tanh(e_sum @ (hidden + vn))
  adj_mm32(es32, es16, use16, hid, vn, (const float*)0, tmp, (float*)0,
           Al, Xt, red, b, it);
  gbar(cnt, 384);
  // phase C: comb (+ gcn for next layer), 16 nodes/block, 4 at a time
  {
    float* cat = Xt;            // 512 floats
    float* nhv = Xt + 512;      // 256 floats
    for (int g2 = 0; g2 < 4; ++g2) {
      int node0 = blk * 16 + g2 * 4;
      __syncthreads();
#pragma unroll
      for (int u = 0; u < 2; ++u) {
        int idx = u * 256 + t;
        int nl = idx >> 7, c = idx & 127;
        int node = node0 + nl;
        int bb = node >> 9;
        cat[idx] = (c < 64) ? hid[node * 64 + c] + vn[bb * 64 + c]
                            : tmp[node * 64 + (c - 64)];
      }
      __syncthreads();
      int nl = t >> 6, h = t & 63;
      float acc = cb[l * 64 + h];
      const float* wp = cw + l * 8192 + h;
      for (int c = 0; c < 128; c += 4) {
        float4 xv = *(const float4*)&cat[nl * 128 + c];
        acc += xv.x * wp[c * 64] + xv.y * wp[(c + 1) * 64]
             + xv.z * wp[(c + 2) * 64] + xv.w * wp[(c + 3) * 64];
      }
      float v = tanh_fast(acc);
      int node = node0 + nl;
      hid[node * 64 + h] = v;
      alls16[node * 256 + (l + 1) * 64 + h] = f2bfs(v);
      if (do_gcn) {
        nhv[t] = v;
        __syncthreads();
        float g = 0.f;
        for (int c = 0; c < 64; ++c) g += nhv[nl * 64 + c] * gw_next[c * 64 + h];
        tmp[node * 64 + h] = g;
      }
    }
  }
}

// ---- latent MLP (8 nodes/block) + fused final head via last-block ------------
__global__ __launch_bounds__(256) void k_latfinal(const u16* __restrict__ alls16,
    const float* __restrict__ w1, const float* __restrict__ bb1,
    const float* __restrict__ w2, const float* __restrict__ bb2,
    float* __restrict__ latpart, int* cnt,
    const float* __restrict__ f1w, const float* __restrict__ f1b,
    const float* __restrict__ f2w, const float* __restrict__ f2b,
    float* __restrict__ outp) {
  __shared__ float x[8][256];
  __shared__ float t1[8][256];
  __shared__ float red[8][256];
  __shared__ int isLastL;
  int t = threadIdx.x;
  int b = blockIdx.x >> 6, chunk = blockIdx.x & 63;
#pragma unroll
  for (int u = 0; u < 8; ++u)
    x[u][t] = bfu(alls16[(size_t)(b * 512 + chunk * 8 + u) * 256 + t]);
  __syncthreads();
  float a1[8];
  float bb = bb1[t];
#pragma unroll
  for (int u = 0; u < 8; ++u) a1[u] = bb;
  for (int c = 0; c < 256; ++c) {
    float wv = w1[c * 256 + t];
#pragma unroll
    for (int u = 0; u < 8; ++u) a1[u] += x[u][c] * wv;
  }
#pragma unroll
  for (int u = 0; u < 8; ++u) t1[u][t] = tanh_fast(a1[u]);
  __syncthreads();
  int quar = t >> 6, k = t & 63, c0 = quar * 64;
  float a2[8];
#pragma unroll
  for (int u = 0; u < 8; ++u) a2[u] = 0.f;
  for (int c = 0; c < 64; ++c) {
    float wv = w2[(c0 + c) * 64 + k];
#pragma unroll
    for (int u = 0; u < 8; ++u) a2[u] += t1[u][c0 + c] * wv;
  }
#pragma unroll
  for (int u = 0; u < 8; ++u) red[u][t] = a2[u];
  __syncthreads();
  if (t < 64) {
    float acc2 = 0.f;
    float b2v = bb2[t];
#pragma unroll
    for (int u = 0; u < 8; ++u) {
      float s = red[u][t] + red[u][t + 64] + red[u][t + 128] + red[u][t + 192] + b2v;
      acc2 += tanh_fast(s);
    }
    latpart[(b * 64 + chunk) * 64 + t] = acc2;
  }
  __threadfence();
  __syncthreads();
  if (t == 0) isLastL = (atomicAdd(cnt, 1) == 255);
  __syncthreads();
  if (isLastL) {
    __threadfence();
    float* ls = &red[0][0];
    float* hb = &x[0][0];
    {
      int bb2_ = t >> 6, z = t & 63;
      float s = 0.f;
      for (int c = 0; c < 64; ++c) s += latpart[(bb2_ * 64 + c) * 64 + z];
      ls[t] = s;
      outp[4 + t] = s;  // lat_sum (fp32)
    }
    __syncthreads();
    for (int rep = 0; rep < 8; ++rep) {
      int idx = rep * 256 + t;
      int bb2_ = idx >> 9, kk = idx & 511;
      float acc = f1b[kk];
      for (int z = 0; z < 64; ++z) acc += ls[bb2_ * 64 + z] * f1w[z * 512 + kk];
      hb[idx] = tanh_fast(acc);
    }
    __syncthreads();
    {
      int bb2_ = t >> 6, lane = t & 63;
      float acc = 0.f;
#pragma unroll
      for (int u = 0; u < 8; ++u) acc += hb[bb2_ * 512 + lane + u * 64] * f2w[lane + u * 64];
#pragma unroll
      for (int off = 32; off > 0; off >>= 1) acc += __shfl_xor(acc, off, 64);
      if (lane == 0) outp[bb2_] = acc + f2b[0];  // predict (fp32)
    }
  }
}

extern "C" void kernel_launch(void* const* d_in, const int* in_sizes, int n_in,
                              void* d_out, int out_size, void* d_ws, size_t ws_size,
                              hipStream_t stream) {
  const float* adj       = (const float*)d_in[0];
  const float* node_feat = (const float*)d_in[1];
  const float* edge_feat = (const float*)d_in[2];
  const float* nf1_w = (const float*)d_in[3];
  const float* nf1_b = (const float*)d_in[4];
  const float* nf2_w = (const float*)d_in[5];
  const float* nf2_b = (const float*)d_in[6];
  const float* ef1_w = (const float*)d_in[7];
  const float* ef1_b = (const float*)d_in[8];
  const float* ef2_w = (const float*)d_in[9];
  const float* ef2_b = (const float*)d_in[10];
  const float* gcn_w = (const float*)d_in[11];
  const float* vn1_w = (const float*)d_in[12];
  const float* vn1_b = (const float*)d_in[13];
  const float* vn1_g = (const float*)d_in[14];
  const float* vn1_be = (const float*)d_in[15];
  const float* vn2_w = (const float*)d_in[16];
  const float* vn2_b = (const float*)d_in[17];
  const float* vn2_g = (const float*)d_in[18];
  const float* vn2_be = (const float*)d_in[19];
  const float* comb_w = (const float*)d_in[20];
  const float* comb_b = (const float*)d_in[21];
  const float* lat1_w = (const float*)d_in[22];
  const float* lat1_b = (const float*)d_in[23];
  const float* lat2_w = (const float*)d_in[24];
  const float* lat2_b = (const float*)d_in[25];
  const float* fc1_w = (const float*)d_in[26];
  const float* fc1_b = (const float*)d_in[27];
  const float* fc2_w = (const float*)d_in[28];
  const float* fc2_b = (const float*)d_in[29];

  const int use16 = (ws_size < (size_t)12 * 1024 * 1024) ? 1 : 0;
  char* p = (char*)d_ws;
  float* es32 = (float*)p;
  u16*   es16 = (u16*)p;
  size_t es_bytes = use16 ? (size_t)1048576 * 2 : (size_t)1048576 * 4;
  u16*   alls16  = (u16*)(p + es_bytes);      // 524288 u16
  float* hid     = (float*)(alls16 + 524288); // 131072 f32
  float* tmp     = hid + 131072;              // 131072
  float* dinv    = tmp + 131072;              // 2048
  float* vnpart  = dinv + 2048;               // 16384 (8192 used)
  float* vn      = vnpart + 16384;            // 256
  float* latpart = vn + 256;                  // 16384
  int*   cnt     = (int*)(latpart + 16384);   // 16

  k_pre<<<512, 256, 0, stream>>>(node_feat, nf1_w, nf1_b, nf2_w, nf2_b,
                                 gcn_w, adj, hid, alls16, tmp, dinv, cnt);
  k_edge<<<1024, 256, 0, stream>>>(edge_feat, ef1_w, ef1_b, ef2_w, ef2_b,
                                   es32, es16, use16);
  for (int l = 0; l < 3; ++l) {
    k_layer<<<128, 256, 0, stream>>>(adj, es32, es16, use16,
        hid, tmp, vn, vnpart, dinv, cnt + l,
        vn1_w, vn1_b, vn1_g, vn1_be, vn2_w, vn2_b, vn2_g, vn2_be,
        comb_w, comb_b, gcn_w + (l + 1) * 4096, alls16, l, (l < 2) ? 1 : 0);
  }
  k_latfinal<<<256, 256, 0, stream>>>(alls16, lat1_w, lat1_b, lat2_w, lat2_b,
                                      latpart, cnt + 3,
                                      fc1_w, fc1_b, fc2_w, fc2_b, (float*)d_out);
}

// Round 8
// 814.779 us; speedup vs baseline: 1.0557x; 1.0557x over previous
//
#include <hip/hip_runtime.h>
#include <math.h>

typedef unsigned short u16;
typedef unsigned int u32;

typedef __attribute__((ext_vector_type(8))) short short8;
typedef __attribute__((ext_vector_type(4))) float floatx4;

#define NTILES 16384  // B*N*N/64

__device__ __forceinline__ float bfu(u16 u) { return __uint_as_float(((u32)u) << 16); }
__device__ __forceinline__ u16 f2bfs(float f) {
  u32 x = __float_as_uint(f);
  return (u16)((x + 0x7FFFu + ((x >> 16) & 1u)) >> 16);
}
__device__ __forceinline__ float tanh_fast(float x) {
  float e = __builtin_amdgcn_exp2f(x * 2.885390081777927f);
  return 1.0f - 2.0f * __builtin_amdgcn_rcpf(e + 1.0f);
}

// ---- device barrier: arrive with RMW, spin on plain agent-scope LOAD ---------
__device__ __forceinline__ void gbar(int* cnt, int target) {
  __threadfence();
  __syncthreads();
  if (threadIdx.x == 0) {
    atomicAdd(cnt, 1);
    while (__hip_atomic_load(cnt, __ATOMIC_RELAXED, __HIP_MEMORY_SCOPE_AGENT) < target)
      __builtin_amdgcn_s_sleep(16);
  }
  __syncthreads();
  __threadfence();
}

// ------ edge MLP -> e_sum: hi/lo-split MFMA layer-1 (fp32-grade) + MFMA layer-2
__global__ __launch_bounds__(256) void k_edge(const float* __restrict__ ef,
    const float* __restrict__ w1, const float* __restrict__ b1,
    const float* __restrict__ w2, const float* __restrict__ b2,
    float* __restrict__ es32, u16* __restrict__ es16, int use16) {
  __shared__ __align__(16) short T1[64 * 264];
  int t = threadIdx.x;
  int lane = t & 63, w = t >> 6, q = lane >> 4, r = lane & 15;

  // stage W2^T (bf16) via T1, preload layer-2 B-frags (unchanged, R5-verified)
  for (int u = 0; u < 64; ++u) {
    int flat = u * 256 + t;          // flat = k*64 + n
    int k = flat >> 6, n = flat & 63;
    T1[n * 264 + k] = (short)f2bfs(w2[flat]);
  }
  __syncthreads();
  short8 bfr2[8][4];
#pragma unroll
  for (int s = 0; s < 8; ++s)
#pragma unroll
    for (int nt = 0; nt < 4; ++nt)
      bfr2[s][nt] = *(const short8*)(&T1[(nt * 16 + r) * 264 + s * 32 + q * 8]);
  __syncthreads();

  // layer-1 split B-frags: slots q0:w_hi q1:w_hi q2:w_lo q3:w_lo (n = nt*16+r)
  short8 bfr1[16];
  float b1v[16];
#pragma unroll
  for (int nt = 0; nt < 16; ++nt) {
    short8 v;
#pragma unroll
    for (int j = 0; j < 8; ++j) {
      float x = w1[j * 256 + nt * 16 + r];
      u32 xb = __float_as_uint(x);
      u16 hi = (u16)(xb >> 16);               // truncated bf16 hi
      float lo = x - bfu(hi);                  // remainder
      v[j] = (q >> 1) ? (short)f2bfs(lo) : (short)hi;
    }
    bfr1[nt] = v;
    b1v[nt] = b1[nt * 16 + r];
  }
  float b2v[4];
#pragma unroll
  for (int nt = 0; nt < 4; ++nt) b2v[nt] = b2[nt * 16 + r];

  for (int tile = blockIdx.x; tile < NTILES; tile += gridDim.x) {
    // ---- layer-1 A-frag from global: edge m = w*16+r; slots q0/q2:e_hi q1/q3:e_lo
    const float4* ep = (const float4*)(ef + (size_t)tile * 512 + (size_t)(w * 16 + r) * 8);
    float4 e0 = ep[0], e1 = ep[1];
    float ev[8] = {e0.x, e0.y, e0.z, e0.w, e1.x, e1.y, e1.z, e1.w};
    short8 af1;
#pragma unroll
    for (int j = 0; j < 8; ++j) {
      u32 xb = __float_as_uint(ev[j]);
      u16 hi = (u16)(xb >> 16);
      af1[j] = (q & 1) ? (short)f2bfs(ev[j] - bfu(hi)) : (short)hi;
    }
    __syncthreads();   // prev tile's layer-2 T1 reads complete
    // ---- layer 1: 16 MFMAs (one per 16-col tile), fp32-accurate split product
#pragma unroll
    for (int g = 0; g < 4; ++g) {
      floatx4 c1[4];
#pragma unroll
      for (int u = 0; u < 4; ++u) {
        float bb = b1v[g * 4 + u];
        c1[u] = (floatx4){bb, bb, bb, bb};
      }
#pragma unroll
      for (int u = 0; u < 4; ++u)
        c1[u] = __builtin_amdgcn_mfma_f32_16x16x32_bf16(af1, bfr1[g * 4 + u], c1[u], 0, 0, 0);
#pragma unroll
      for (int u = 0; u < 4; ++u)
#pragma unroll
        for (int reg = 0; reg < 4; ++reg)
          T1[(w * 16 + q * 4 + reg) * 264 + (g * 4 + u) * 16 + r] =
              (short)f2bfs(tanh_fast(c1[u][reg]));
    }
    __syncthreads();
    // ---- layer 2 via MFMA (unchanged from R5/R7) ----
    floatx4 acc4[4];
#pragma unroll
    for (int nt = 0; nt < 4; ++nt) acc4[nt] = (floatx4){0.f, 0.f, 0.f, 0.f};
    const short* arow = &T1[(w * 16 + r) * 264];
#pragma unroll
    for (int s = 0; s < 8; ++s) {
      short8 af = *(const short8*)(arow + s * 32 + q * 8);
#pragma unroll
      for (int nt = 0; nt < 4; ++nt)
        acc4[nt] = __builtin_amdgcn_mfma_f32_16x16x32_bf16(af, bfr2[s][nt], acc4[nt], 0, 0, 0);
    }
    float s0 = 0.f, s1 = 0.f, s2 = 0.f, s3 = 0.f;
#pragma unroll
    for (int nt = 0; nt < 4; ++nt) {
      float bb = b2v[nt];
      s0 += tanh_fast(acc4[nt][0] + bb);
      s1 += tanh_fast(acc4[nt][1] + bb);
      s2 += tanh_fast(acc4[nt][2] + bb);
      s3 += tanh_fast(acc4[nt][3] + bb);
    }
#pragma unroll
    for (int off = 1; off < 16; off <<= 1) {
      s0 += __shfl_xor(s0, off, 64);
      s1 += __shfl_xor(s1, off, 64);
      s2 += __shfl_xor(s2, off, 64);
      s3 += __shfl_xor(s3, off, 64);
    }
    if (r == 0) {
      int base = tile * 64 + w * 16 + q * 4;
      if (use16) {
        es16[base] = f2bfs(s0); es16[base + 1] = f2bfs(s1);
        es16[base + 2] = f2bfs(s2); es16[base + 3] = f2bfs(s3);
      } else {
        float4 o; o.x = s0; o.y = s1; o.z = s2; o.w = s3;
        *(float4*)&es32[base] = o;
      }
    }
  }
}

// ---- k_pre: node embed MLP + gcn_tmp(l=0) + dinv + counter zero --------------
__global__ __launch_bounds__(256) void k_pre(const float* __restrict__ nf,
    const float* __restrict__ w1, const float* __restrict__ b1,
    const float* __restrict__ w2, const float* __restrict__ b2,
    const float* __restrict__ gw, const float* __restrict__ adj,
    u16* __restrict__ alls16, float* __restrict__ tmp,
    float* __restrict__ dinv, int* __restrict__ cnt) {
  __shared__ float nfx[4][16];
  __shared__ float t1[4][256];
  __shared__ float nh[4][64];
  int t = threadIdx.x;
  int node0 = blockIdx.x * 4;
  if (blockIdx.x == 0 && t < 16) cnt[t] = 0;
  if (t < 64) nfx[t >> 4][t & 15] = nf[node0 * 16 + t];
  __syncthreads();
  float b1t = b1[t];
  float a0 = b1t, a1 = b1t, a2 = b1t, a3 = b1t;
#pragma unroll
  for (int c = 0; c < 16; ++c) {
    float wv = w1[c * 256 + t];
    a0 += nfx[0][c] * wv; a1 += nfx[1][c] * wv;
    a2 += nfx[2][c] * wv; a3 += nfx[3][c] * wv;
  }
  t1[0][t] = tanh_fast(a0); t1[1][t] = tanh_fast(a1);
  t1[2][t] = tanh_fast(a2); t1[3][t] = tanh_fast(a3);
  __syncthreads();
  int nl = t >> 6, h = t & 63;
  {
    float acc = b2[h];
    for (int c = 0; c < 256; c += 4) {
      float4 xv = *(const float4*)&t1[nl][c];
      acc += xv.x * w2[c * 64 + h] + xv.y * w2[(c + 1) * 64 + h]
           + xv.z * w2[(c + 2) * 64 + h] + xv.w * w2[(c + 3) * 64 + h];
    }
    float v = tanh_fast(acc);
    int node = node0 + nl;
    alls16[node * 256 + h] = f2bfs(v);
    nh[nl][h] = v;
  }
  __syncthreads();
  {
    float g = 0.f;
    for (int c = 0; c < 64; ++c) g += nh[nl][c] * gw[c * 64 + h];
    tmp[(node0 + nl) * 64 + h] = g;
  }
  {
    int lane = t & 63, row = node0 + (t >> 6);
    float s = 0.f;
#pragma unroll
    for (int u = 0; u < 8; ++u) s += adj[(size_t)row * 512 + u * 64 + lane];
#pragma unroll
    for (int off = 32; off > 0; off >>= 1) s += __shfl_xor(s, off, 64);
    if (lane == 0) dinv[row] = 1.0f / (s + 1.0f);
  }
}

// ---- fp32 VALU adjacency matmul (R5 summation order), 16 rows/block ----------
__device__ __forceinline__ void adj_mm32(const float* __restrict__ Af,
    const u16* __restrict__ A16, int useA16,
    const float* __restrict__ X, const float* vnadd,
    const float* __restrict__ dinv, float* __restrict__ out,
    float* __restrict__ vnpart, float* Al, float* Xt, float* red,
    int b, int it) {
  int t = threadIdx.x;
  int row = t >> 4, cq = t & 15;
  floatx4 acc = (floatx4){0.f, 0.f, 0.f, 0.f};
  for (int jt = 0; jt < 8; ++jt) {
    __syncthreads();
#pragma unroll
    for (int u = 0; u < 4; ++u) {        // A tile 16x64 -> Al[row*65+k]
      int idx = u * 256 + t;
      int rr = idx >> 6, kk = idx & 63;
      size_t ai = ((size_t)(b * 512 + it * 16 + rr)) * 512 + jt * 64 + kk;
      Al[rr * 65 + kk] = useA16 ? bfu(A16[ai]) : Af[ai];
    }
#pragma unroll
    for (int u = 0; u < 16; ++u) {       // X tile 64x64, k-major fp32
      int idx = u * 256 + t;
      int kk = idx >> 6, n = idx & 63;
      float xv = X[(size_t)(b * 512 + jt * 64 + kk) * 64 + n];
      if (vnadd) xv += vnadd[b * 64 + n];
      Xt[kk * 64 + n] = xv;
    }
    __syncthreads();
    const float* ap = &Al[row * 65];
    const float* xp = &Xt[cq * 4];
#pragma unroll 8
    for (int jl = 0; jl < 64; ++jl) {
      float a = ap[jl];
      floatx4 xv = *(const floatx4*)(xp + jl * 64);
      acc[0] += a * xv[0]; acc[1] += a * xv[1];
      acc[2] += a * xv[2]; acc[3] += a * xv[3];
    }
  }
  int grow = b * 512 + it * 16 + row;
  floatx4 o;
  if (dinv) {
    float d = dinv[grow];
#pragma unroll
    for (int i = 0; i < 4; ++i) o[i] = tanh_fast(acc[i] * d);
  } else {
#pragma unroll
    for (int i = 0; i < 4; ++i) o[i] = tanh_fast(acc[i]);
  }
  *(floatx4*)&out[(size_t)grow * 64 + cq * 4] = o;
  if (vnpart) {
    *(floatx4*)&red[row * 64 + cq * 4] = o;   // red keeps own 16 rows for phase C
    __syncthreads();
    if (t < 64) {
      float s = 0.f;
#pragma unroll
      for (int rr = 0; rr < 16; ++rr) s += red[rr * 64 + t];
      vnpart[(b * 32 + it) * 64 + t] = s;
    }
  }
}

// ---- fused layer, ONE device barrier: A -> [all-block vn_mlp] -> B -> C ------
__global__ __launch_bounds__(256) void k_layer(const float* __restrict__ adj,
    const float* __restrict__ es32, const u16* __restrict__ es16, int use16,
    float* hmid, float* tmp, float* __restrict__ vnpart,
    const float* __restrict__ dinv, int* cnt,
    const float* __restrict__ vw1, const float* __restrict__ vb1,
    const float* __restrict__ vg1, const float* __restrict__ vbe1,
    const float* __restrict__ vw2, const float* __restrict__ vb2,
    const float* __restrict__ vg2, const float* __restrict__ vbe2,
    const float* __restrict__ cw, const float* __restrict__ cb,
    const float* __restrict__ gw_next, u16* __restrict__ alls16,
    int l, int do_gcn) {
  __shared__ __align__(16) float Al[16 * 65];
  __shared__ __align__(16) float Xt[64 * 64];
  __shared__ __align__(16) float red[16 * 64];
  __shared__ float vnL[256];
  int t = threadIdx.x;
  int blk = blockIdx.x;
  int b = blk >> 5, it = blk & 31;

  // phase A: hmid = tanh(dinv * adj @ tmp); red <- own 16 rows; vnpart partials
  adj_mm32(adj, (const u16*)0, 0, tmp, (const float*)0, dinv, hmid, vnpart,
           Al, Xt, red, b, it);
  gbar(cnt, 128);   // the ONLY device barrier this layer

  // vn_mlp computed redundantly by EVERY block (reads global vnpart -> vnL)
  {
    float* x0 = Xt; float* x1 = Xt + 256; float* y1 = Xt + 768; float* x2 = Xt + 1280;
    {
      int bb = t >> 6, h = t & 63;
      float s = 0.f;
      for (int c = 0; c < 32; ++c) s += vnpart[(bb * 32 + c) * 64 + h];
      x0[t] = s * (1.0f / 512.0f);
    }
    __syncthreads();
    for (int rep = 0; rep < 2; ++rep) {
      int idx = rep * 256 + t;
      int bb = idx >> 7, j = idx & 127;
      float a = vb1[l * 128 + j];
      for (int h = 0; h < 64; ++h) a += x0[bb * 64 + h] * vw1[l * 8192 + h * 128 + j];
      x1[idx] = a;
    }
    __syncthreads();
    if (t < 128) {
      int j = t;
      float a = x1[j], bq = x1[128 + j], c = x1[256 + j], d = x1[384 + j];
      float m = 0.25f * (a + bq + c + d);
      float da = a - m, db = bq - m, dc = c - m, dd = d - m;
      float var = 0.25f * (da * da + db * db + dc * dc + dd * dd);
      float sc = vg1[l * 128 + j] / sqrtf(var + 1e-5f);
      float be = vbe1[l * 128 + j];
      y1[j]       = fmaxf(sc * da + be, 0.f);
      y1[128 + j] = fmaxf(sc * db + be, 0.f);
      y1[256 + j] = fmaxf(sc * dc + be, 0.f);
      y1[384 + j] = fmaxf(sc * dd + be, 0.f);
    }
    __syncthreads();
    {
      int bb = t >> 6, k = t & 63;
      float a = vb2[l * 64 + k];
      for (int j = 0; j < 128; ++j) a += y1[bb * 128 + j] * vw2[l * 8192 + j * 64 + k];
      x2[t] = a;
    }
    __syncthreads();
    if (t < 64) {
      int k = t;
      float a = x2[k], bq = x2[64 + k], c = x2[128 + k], d = x2[192 + k];
      float m = 0.25f * (a + bq + c + d);
      float da = a - m, db = bq - m, dc = c - m, dd = d - m;
      float var = 0.25f * (da * da + db * db + dc * dc + dd * dd);
      float sc = vg2[l * 64 + k] / sqrtf(var + 1e-5f);
      float be = vbe2[l * 64 + k];
      vnL[k]       = fmaxf(sc * da + be, 0.f);
      vnL[64 + k]  = fmaxf(sc * db + be, 0.f);
      vnL[128 + k] = fmaxf(sc * dc + be, 0.f);
      vnL[192 + k] = fmaxf(sc * dd + be, 0.f);
    }
  }
  __syncthreads();
  // phase B: tmp(own rows) = gated = tanh(e_sum @ (hmid + vn)); red untouched
  adj_mm32(es32, es16, use16, hmid, vnL, (const float*)0, tmp, (float*)0,
           Al, Xt, red, b, it);
  __syncthreads();
  // phase C: block-local — hid+vn from red/vnL, gated from own tmp rows
  {
    float* cat = Xt;
    float* nhv = Xt + 512;
    for (int g2 = 0; g2 < 4; ++g2) {
      int node0 = blk * 16 + g2 * 4;
      __syncthreads();
#pragma unroll
      for (int u = 0; u < 2; ++u) {
        int idx = u * 256 + t;
        int nl = idx >> 7, c = idx & 127;
        int node = node0 + nl;
        cat[idx] = (c < 64) ? red[(g2 * 4 + nl) * 64 + c] + vnL[(node >> 9) * 64 + c]
                            : tmp[node * 64 + (c - 64)];
      }
      __syncthreads();
      int nl = t >> 6, h = t & 63;
      float acc = cb[l * 64 + h];
      const float* wp = cw + l * 8192 + h;
      for (int c = 0; c < 128; c += 4) {
        float4 xv = *(const float4*)&cat[nl * 128 + c];
        acc += xv.x * wp[c * 64] + xv.y * wp[(c + 1) * 64]
             + xv.z * wp[(c + 2) * 64] + xv.w * wp[(c + 3) * 64];
      }
      float v = tanh_fast(acc);
      int node = node0 + nl;
      alls16[node * 256 + (l + 1) * 64 + h] = f2bfs(v);
      if (do_gcn) {
        nhv[t] = v;
        __syncthreads();
        float g = 0.f;
        for (int c = 0; c < 64; ++c) g += nhv[nl * 64 + c] * gw_next[c * 64 + h];
        tmp[node * 64 + h] = g;
      }
    }
  }
}

// ---- latent MLP (8 nodes/block) + fused final head via last-block ------------
__global__ __launch_bounds__(256) void k_latfinal(const u16* __restrict__ alls16,
    const float* __restrict__ w1, const float* __restrict__ bb1,
    const float* __restrict__ w2, const float* __restrict__ bb2,
    float* __restrict__ latpart, int* cnt,
    const float* __restrict__ f1w, const float* __restrict__ f1b,
    const float* __restrict__ f2w, const float* __restrict__ f2b,
    float* __restrict__ outp) {
  __shared__ float x[8][256];
  __shared__ float t1[8][256];
  __shared__ float red[8][256];
  __shared__ int isLastL;
  int t = threadIdx.x;
  int b = blockIdx.x >> 6, chunk = blockIdx.x & 63;
#pragma unroll
  for (int u = 0; u < 8; ++u)
    x[u][t] = bfu(alls16[(size_t)(b * 512 + chunk * 8 + u) * 256 + t]);
  __syncthreads();
  float a1[8];
  float bb = bb1[t];
#pragma unroll
  for (int u = 0; u < 8; ++u) a1[u] = bb;
  for (int c = 0; c < 256; ++c) {
    float wv = w1[c * 256 + t];
#pragma unroll
    for (int u = 0; u < 8; ++u) a1[u] += x[u][c] * wv;
  }
#pragma unroll
  for (int u = 0; u < 8; ++u) t1[u][t] = tanh_fast(a1[u]);
  __syncthreads();
  int quar = t >> 6, k = t & 63, c0 = quar * 64;
  float a2[8];
#pragma unroll
  for (int u = 0; u < 8; ++u) a2[u] = 0.f;
  for (int c = 0; c < 64; ++c) {
    float wv = w2[(c0 + c) * 64 + k];
#pragma unroll
    for (int u = 0; u < 8; ++u) a2[u] += t1[u][c0 + c] * wv;
  }
#pragma unroll
  for (int u = 0; u < 8; ++u) red[u][t] = a2[u];
  __syncthreads();
  if (t < 64) {
    float acc2 = 0.f;
    float b2v = bb2[t];
#pragma unroll
    for (int u = 0; u < 8; ++u) {
      float s = red[u][t] + red[u][t + 64] + red[u][t + 128] + red[u][t + 192] + b2v;
      acc2 += tanh_fast(s);
    }
    latpart[(b * 64 + chunk) * 64 + t] = acc2;
  }
  __threadfence();
  __syncthreads();
  if (t == 0) isLastL = (atomicAdd(cnt, 1) == 255);
  __syncthreads();
  if (isLastL) {
    __threadfence();
    float* ls = &red[0][0];
    float* hb = &x[0][0];
    {
      int bb2_ = t >> 6, z = t & 63;
      float s = 0.f;
      for (int c = 0; c < 64; ++c) s += latpart[(bb2_ * 64 + c) * 64 + z];
      ls[t] = s;
      outp[4 + t] = s;  // lat_sum (fp32)
    }
    __syncthreads();
    for (int rep = 0; rep < 8; ++rep) {
      int idx = rep * 256 + t;
      int bb2_ = idx >> 9, kk = idx & 511;
      float acc = f1b[kk];
      for (int z = 0; z < 64; ++z) acc += ls[bb2_ * 64 + z] * f1w[z * 512 + kk];
      hb[idx] = tanh_fast(acc);
    }
    __syncthreads();
    {
      int bb2_ = t >> 6, lane = t & 63;
      float acc = 0.f;
#pragma unroll
      for (int u = 0; u < 8; ++u) acc += hb[bb2_ * 512 + lane + u * 64] * f2w[lane + u * 64];
#pragma unroll
      for (int off = 32; off > 0; off >>= 1) acc += __shfl_xor(acc, off, 64);
      if (lane == 0) outp[bb2_] = acc + f2b[0];  // predict (fp32)
    }
  }
}

extern "C" void kernel_launch(void* const* d_in, const int* in_sizes, int n_in,
                              void* d_out, int out_size, void* d_ws, size_t ws_size,
                              hipStream_t stream) {
  const float* adj       = (const float*)d_in[0];
  const float* node_feat = (const float*)d_in[1];
  const float* edge_feat = (const float*)d_in[2];
  const float* nf1_w = (const float*)d_in[3];
  const float* nf1_b = (const float*)d_in[4];
  const float* nf2_w = (const float*)d_in[5];
  const float* nf2_b = (const float*)d_in[6];
  const float* ef1_w = (const float*)d_in[7];
  const float* ef1_b = (const float*)d_in[8];
  const float* ef2_w = (const float*)d_in[9];
  const float* ef2_b = (const float*)d_in[10];
  const float* gcn_w = (const float*)d_in[11];
  const float* vn1_w = (const float*)d_in[12];
  const float* vn1_b = (const float*)d_in[13];
  const float* vn1_g = (const float*)d_in[14];
  const float* vn1_be = (const float*)d_in[15];
  const float* vn2_w = (const float*)d_in[16];
  const float* vn2_b = (const float*)d_in[17];
  const float* vn2_g = (const float*)d_in[18];
  const float* vn2_be = (const float*)d_in[19];
  const float* comb_w = (const float*)d_in[20];
  const float* comb_b = (const float*)d_in[21];
  const float* lat1_w = (const float*)d_in[22];
  const float* lat1_b = (const float*)d_in[23];
  const float* lat2_w = (const float*)d_in[24];
  const float* lat2_b = (const float*)d_in[25];
  const float* fc1_w = (const float*)d_in[26];
  const float* fc1_b = (const float*)d_in[27];
  const float* fc2_w = (const float*)d_in[28];
  const float* fc2_b = (const float*)d_in[29];

  const int use16 = (ws_size < (size_t)12 * 1024 * 1024) ? 1 : 0;
  char* p = (char*)d_ws;
  float* es32 = (float*)p;
  u16*   es16 = (u16*)p;
  size_t es_bytes = use16 ? (size_t)1048576 * 2 : (size_t)1048576 * 4;
  u16*   alls16  = (u16*)(p + es_bytes);      // 524288 u16
  float* hmid    = (float*)(alls16 + 524288); // 131072 f32
  float* tmp     = hmid + 131072;             // 131072
  float* dinv    = tmp + 131072;              // 2048
  float* vnpart  = dinv + 2048;               // 16384 (8192 used)
  float* vn_unused = vnpart + 16384;          // 256 (kept for layout stability)
  float* latpart = vn_unused + 256;           // 16384
  int*   cnt     = (int*)(latpart + 16384);   // 16

  k_pre<<<512, 256, 0, stream>>>(node_feat, nf1_w, nf1_b, nf2_w, nf2_b,
                                 gcn_w, adj, alls16, tmp, dinv, cnt);
  k_edge<<<1024, 256, 0, stream>>>(edge_feat, ef1_w, ef1_b, ef2_w, ef2_b,
                                   es32, es16, use16);
  for (int l = 0; l < 3; ++l) {
    k_layer<<<128, 256, 0, stream>>>(adj, es32, es16, use16,
        hmid, tmp, vnpart, dinv, cnt + l,
        vn1_w, vn1_b, vn1_g, vn1_be, vn2_w, vn2_b, vn2_g, vn2_be,
        comb_w, comb_b, gcn_w + (l + 1) * 4096, alls16, l, (l < 2) ? 1 : 0);
  }
  k_latfinal<<<256, 256, 0, stream>>>(alls16, lat1_w, lat1_b, lat2_w, lat2_b,
                                      latpart, cnt + 3,
                                      fc1_w, fc1_b, fc2_w, fc2_b, (float*)d_out);
}

// Round 9
// 753.211 us; speedup vs baseline: 1.1420x; 1.0817x over previous
//
#include <hip/hip_runtime.h>
#include <math.h>

typedef unsigned short u16;
typedef unsigned int u32;

typedef __attribute__((ext_vector_type(8))) short short8;
typedef __attribute__((ext_vector_type(4))) float floatx4;

#define NTILES 16384  // B*N*N/64

__device__ __forceinline__ float bfu(u16 u) { return __uint_as_float(((u32)u) << 16); }
__device__ __forceinline__ u16 f2bfs(float f) {
  u32 x = __float_as_uint(f);
  return (u16)((x + 0x7FFFu + ((x >> 16) & 1u)) >> 16);
}
__device__ __forceinline__ float tanh_fast(float x) {
  float e = __builtin_amdgcn_exp2f(x * 2.885390081777927f);
  return 1.0f - 2.0f * __builtin_amdgcn_rcpf(e + 1.0f);
}

// ---- device barrier: coherent RMW poll, heavily throttled --------------------
// RMW (atomicAdd(p,0)) is the only guaranteed-coherent read across the
// non-coherent per-XCD L2s (G16). s_sleep(64) ~ 4096 cyc between polls keeps
// 128 pollers to ~1 RMW / 32 cyc at the line's home bank — no storm.
__device__ __forceinline__ void gbar(int* cnt, int target) {
  __threadfence();
  __syncthreads();
  if (threadIdx.x == 0) {
    atomicAdd(cnt, 1);
    while (atomicAdd(cnt, 0) < target) __builtin_amdgcn_s_sleep(64);
  }
  __syncthreads();
  __threadfence();
}

// ------------- edge MLP -> e_sum: R5-exact kernel (fp32 layer-1) --------------
__global__ __launch_bounds__(256) void k_edge(const float* __restrict__ ef,
    const float* __restrict__ w1, const float* __restrict__ b1,
    const float* __restrict__ w2, const float* __restrict__ b2,
    float* __restrict__ es32, u16* __restrict__ es16, int use16) {
  __shared__ __align__(16) short T1[64 * 264];
  __shared__ __align__(16) float EF[8 * 64];
  int t = threadIdx.x;
  int lane = t & 63, w = t >> 6, q = lane >> 4, r = lane & 15;

  for (int u = 0; u < 64; ++u) {
    int flat = u * 256 + t;          // flat = k*64 + n
    int k = flat >> 6, n = flat & 63;
    T1[n * 264 + k] = (short)f2bfs(w2[flat]);
  }
  __syncthreads();
  short8 bfr2[8][4];
#pragma unroll
  for (int s = 0; s < 8; ++s)
#pragma unroll
    for (int nt = 0; nt < 4; ++nt)
      bfr2[s][nt] = *(const short8*)(&T1[(nt * 16 + r) * 264 + s * 32 + q * 8]);
  __syncthreads();

  float w1c[8];
#pragma unroll
  for (int c = 0; c < 8; ++c) w1c[c] = w1[c * 256 + t];
  float b1t = b1[t];
  float b2v[4];
#pragma unroll
  for (int nt = 0; nt < 4; ++nt) b2v[nt] = b2[nt * 16 + r];

  for (int tile = blockIdx.x; tile < NTILES; tile += gridDim.x) {
    {
      int m = t >> 2, c = (t & 3) * 2;
      float2 e2 = *(const float2*)(ef + (size_t)tile * 512 + m * 8 + c);
      EF[c * 64 + m] = e2.x;
      EF[(c + 1) * 64 + m] = e2.y;
    }
    __syncthreads();
    for (int mt = 0; mt < 8; ++mt) {
      float acc[8];
#pragma unroll
      for (int mm = 0; mm < 8; ++mm) acc[mm] = b1t;
#pragma unroll
      for (int c = 0; c < 8; ++c) {
        const float4* ep = (const float4*)&EF[c * 64 + mt * 8];
        float4 ea = ep[0], eb = ep[1];
        float wv = w1c[c];
        acc[0] += ea.x * wv; acc[1] += ea.y * wv; acc[2] += ea.z * wv; acc[3] += ea.w * wv;
        acc[4] += eb.x * wv; acc[5] += eb.y * wv; acc[6] += eb.z * wv; acc[7] += eb.w * wv;
      }
#pragma unroll
      for (int mm = 0; mm < 8; ++mm)
        T1[(mt * 8 + mm) * 264 + t] = (short)f2bfs(tanh_fast(acc[mm]));
    }
    __syncthreads();
    floatx4 acc4[4];
#pragma unroll
    for (int nt = 0; nt < 4; ++nt) acc4[nt] = (floatx4){0.f, 0.f, 0.f, 0.f};
    const short* arow = &T1[(w * 16 + r) * 264];
#pragma unroll
    for (int s = 0; s < 8; ++s) {
      short8 af = *(const short8*)(arow + s * 32 + q * 8);
#pragma unroll
      for (int nt = 0; nt < 4; ++nt)
        acc4[nt] = __builtin_amdgcn_mfma_f32_16x16x32_bf16(af, bfr2[s][nt], acc4[nt], 0, 0, 0);
    }
    float s0 = 0.f, s1 = 0.f, s2 = 0.f, s3 = 0.f;
#pragma unroll
    for (int nt = 0; nt < 4; ++nt) {
      float bb = b2v[nt];
      s0 += tanh_fast(acc4[nt][0] + bb);
      s1 += tanh_fast(acc4[nt][1] + bb);
      s2 += tanh_fast(acc4[nt][2] + bb);
      s3 += tanh_fast(acc4[nt][3] + bb);
    }
#pragma unroll
    for (int off = 1; off < 16; off <<= 1) {
      s0 += __shfl_xor(s0, off, 64);
      s1 += __shfl_xor(s1, off, 64);
      s2 += __shfl_xor(s2, off, 64);
      s3 += __shfl_xor(s3, off, 64);
    }
    if (r == 0) {
      int base = tile * 64 + w * 16 + q * 4;
      if (use16) {
        es16[base] = f2bfs(s0); es16[base + 1] = f2bfs(s1);
        es16[base + 2] = f2bfs(s2); es16[base + 3] = f2bfs(s3);
      } else {
        float4 o; o.x = s0; o.y = s1; o.z = s2; o.w = s3;
        *(float4*)&es32[base] = o;
      }
    }
    __syncthreads();  // REQUIRED: EF restage vs prev-tile reads
  }
}

// ---- k_pre: node embed MLP + gcn_tmp(l=0) + dinv + counter zero --------------
__global__ __launch_bounds__(256) void k_pre(const float* __restrict__ nf,
    const float* __restrict__ w1, const float* __restrict__ b1,
    const float* __restrict__ w2, const float* __restrict__ b2,
    const float* __restrict__ gw, const float* __restrict__ adj,
    u16* __restrict__ alls16, float* __restrict__ tmp,
    float* __restrict__ dinv, int* __restrict__ cnt) {
  __shared__ float nfx[4][16];
  __shared__ float t1[4][256];
  __shared__ float nh[4][64];
  int t = threadIdx.x;
  int node0 = blockIdx.x * 4;
  if (blockIdx.x == 0 && t < 16) cnt[t] = 0;
  if (t < 64) nfx[t >> 4][t & 15] = nf[node0 * 16 + t];
  __syncthreads();
  float b1t = b1[t];
  float a0 = b1t, a1 = b1t, a2 = b1t, a3 = b1t;
#pragma unroll
  for (int c = 0; c < 16; ++c) {
    float wv = w1[c * 256 + t];
    a0 += nfx[0][c] * wv; a1 += nfx[1][c] * wv;
    a2 += nfx[2][c] * wv; a3 += nfx[3][c] * wv;
  }
  t1[0][t] = tanh_fast(a0); t1[1][t] = tanh_fast(a1);
  t1[2][t] = tanh_fast(a2); t1[3][t] = tanh_fast(a3);
  __syncthreads();
  int nl = t >> 6, h = t & 63;
  {
    float acc = b2[h];
    for (int c = 0; c < 256; c += 4) {
      float4 xv = *(const float4*)&t1[nl][c];
      acc += xv.x * w2[c * 64 + h] + xv.y * w2[(c + 1) * 64 + h]
           + xv.z * w2[(c + 2) * 64 + h] + xv.w * w2[(c + 3) * 64 + h];
    }
    float v = tanh_fast(acc);
    int node = node0 + nl;
    alls16[node * 256 + h] = f2bfs(v);
    nh[nl][h] = v;
  }
  __syncthreads();
  {
    float g = 0.f;
    for (int c = 0; c < 64; ++c) g += nh[nl][c] * gw[c * 64 + h];
    tmp[(node0 + nl) * 64 + h] = g;
  }
  {
    int lane = t & 63, row = node0 + (t >> 6);
    float s = 0.f;
#pragma unroll
    for (int u = 0; u < 8; ++u) s += adj[(size_t)row * 512 + u * 64 + lane];
#pragma unroll
    for (int off = 32; off > 0; off >>= 1) s += __shfl_xor(s, off, 64);
    if (lane == 0) dinv[row] = 1.0f / (s + 1.0f);
  }
}

// ---- fp32 VALU adjacency matmul (R5 summation order), 16 rows/block ----------
__device__ __forceinline__ void adj_mm32(const float* __restrict__ Af,
    const u16* __restrict__ A16, int useA16,
    const float* __restrict__ X, const float* vnadd,
    const float* __restrict__ dinv, float* __restrict__ out,
    float* __restrict__ vnpart, float* Al, float* Xt, float* red,
    int b, int it) {
  int t = threadIdx.x;
  int row = t >> 4, cq = t & 15;
  floatx4 acc = (floatx4){0.f, 0.f, 0.f, 0.f};
  for (int jt = 0; jt < 8; ++jt) {
    __syncthreads();
#pragma unroll
    for (int u = 0; u < 4; ++u) {        // A tile 16x64 -> Al[row*65+k]
      int idx = u * 256 + t;
      int rr = idx >> 6, kk = idx & 63;
      size_t ai = ((size_t)(b * 512 + it * 16 + rr)) * 512 + jt * 64 + kk;
      Al[rr * 65 + kk] = useA16 ? bfu(A16[ai]) : Af[ai];
    }
#pragma unroll
    for (int u = 0; u < 16; ++u) {       // X tile 64x64, k-major fp32
      int idx = u * 256 + t;
      int kk = idx >> 6, n = idx & 63;
      float xv = X[(size_t)(b * 512 + jt * 64 + kk) * 64 + n];
      if (vnadd) xv += vnadd[b * 64 + n];
      Xt[kk * 64 + n] = xv;
    }
    __syncthreads();
    const float* ap = &Al[row * 65];
    const float* xp = &Xt[cq * 4];
#pragma unroll 8
    for (int jl = 0; jl < 64; ++jl) {
      float a = ap[jl];
      floatx4 xv = *(const floatx4*)(xp + jl * 64);
      acc[0] += a * xv[0]; acc[1] += a * xv[1];
      acc[2] += a * xv[2]; acc[3] += a * xv[3];
    }
  }
  int grow = b * 512 + it * 16 + row;
  floatx4 o;
  if (dinv) {
    float d = dinv[grow];
#pragma unroll
    for (int i = 0; i < 4; ++i) o[i] = tanh_fast(acc[i] * d);
  } else {
#pragma unroll
    for (int i = 0; i < 4; ++i) o[i] = tanh_fast(acc[i]);
  }
  *(floatx4*)&out[(size_t)grow * 64 + cq * 4] = o;
  if (vnpart) {
    *(floatx4*)&red[row * 64 + cq * 4] = o;   // red keeps own 16 rows for phase C
    __syncthreads();
    if (t < 64) {
      float s = 0.f;
#pragma unroll
      for (int rr = 0; rr < 16; ++rr) s += red[rr * 64 + t];
      vnpart[(b * 32 + it) * 64 + t] = s;
    }
  }
}

// ---- fused layer, ONE device barrier: A -> [all-block vn_mlp] -> B -> C ------
__global__ __launch_bounds__(256) void k_layer(const float* __restrict__ adj,
    const float* __restrict__ es32, const u16* __restrict__ es16, int use16,
    float* hmid, float* tmp, float* __restrict__ vnpart,
    const float* __restrict__ dinv, int* cnt,
    const float* __restrict__ vw1, const float* __restrict__ vb1,
    const float* __restrict__ vg1, const float* __restrict__ vbe1,
    const float* __restrict__ vw2, const float* __restrict__ vb2,
    const float* __restrict__ vg2, const float* __restrict__ vbe2,
    const float* __restrict__ cw, const float* __restrict__ cb,
    const float* __restrict__ gw_next, u16* __restrict__ alls16,
    int l, int do_gcn) {
  __shared__ __align__(16) float Al[16 * 65];
  __shared__ __align__(16) float Xt[64 * 64];
  __shared__ __align__(16) float red[16 * 64];
  __shared__ float vnL[256];
  int t = threadIdx.x;
  int blk = blockIdx.x;
  int b = blk >> 5, it = blk & 31;

  // phase A: hmid = tanh(dinv * adj @ tmp); red <- own 16 rows; vnpart partials
  adj_mm32(adj, (const u16*)0, 0, tmp, (const float*)0, dinv, hmid, vnpart,
           Al, Xt, red, b, it);
  gbar(cnt, 128);   // the ONLY device barrier this layer

  // vn_mlp computed redundantly by EVERY block (reads global vnpart -> vnL)
  {
    float* x0 = Xt; float* x1 = Xt + 256; float* y1 = Xt + 768; float* x2 = Xt + 1280;
    {
      int bb = t >> 6, h = t & 63;
      float s = 0.f;
      for (int c = 0; c < 32; ++c) s += vnpart[(bb * 32 + c) * 64 + h];
      x0[t] = s * (1.0f / 512.0f);
    }
    __syncthreads();
    for (int rep = 0; rep < 2; ++rep) {
      int idx = rep * 256 + t;
      int bb = idx >> 7, j = idx & 127;
      float a = vb1[l * 128 + j];
      for (int h = 0; h < 64; ++h) a += x0[bb * 64 + h] * vw1[l * 8192 + h * 128 + j];
      x1[idx] = a;
    }
    __syncthreads();
    if (t < 128) {
      int j = t;
      float a = x1[j], bq = x1[128 + j], c = x1[256 + j], d = x1[384 + j];
      float m = 0.25f * (a + bq + c + d);
      float da = a - m, db = bq - m, dc = c - m, dd = d - m;
      float var = 0.25f * (da * da + db * db + dc * dc + dd * dd);
      float sc = vg1[l * 128 + j] / sqrtf(var + 1e-5f);
      float be = vbe1[l * 128 + j];
      y1[j]       = fmaxf(sc * da + be, 0.f);
      y1[128 + j] = fmaxf(sc * db + be, 0.f);
      y1[256 + j] = fmaxf(sc * dc + be, 0.f);
      y1[384 + j] = fmaxf(sc * dd + be, 0.f);
    }
    __syncthreads();
    {
      int bb = t >> 6, k = t & 63;
      float a = vb2[l * 64 + k];
      for (int j = 0; j < 128; ++j) a += y1[bb * 128 + j] * vw2[l * 8192 + j * 64 + k];
      x2[t] = a;
    }
    __syncthreads();
    if (t < 64) {
      int k = t;
      float a = x2[k], bq = x2[64 + k], c = x2[128 + k], d = x2[192 + k];
      float m = 0.25f * (a + bq + c + d);
      float da = a - m, db = bq - m, dc = c - m, dd = d - m;
      float var = 0.25f * (da * da + db * db + dc * dc + dd * dd);
      float sc = vg2[l * 64 + k] / sqrtf(var + 1e-5f);
      float be = vbe2[l * 64 + k];
      vnL[k]       = fmaxf(sc * da + be, 0.f);
      vnL[64 + k]  = fmaxf(sc * db + be, 0.f);
      vnL[128 + k] = fmaxf(sc * dc + be, 0.f);
      vnL[192 + k] = fmaxf(sc * dd + be, 0.f);
    }
  }
  __syncthreads();
  // phase B: tmp(own rows) = gated = tanh(e_sum @ (hmid + vn)); red untouched
  adj_mm32(es32, es16, use16, hmid, vnL, (const float*)0, tmp, (float*)0,
           Al, Xt, red, b, it);
  __syncthreads();
  // phase C: block-local — hid+vn from red/vnL, gated from own tmp rows
  {
    float* cat = Xt;
    float* nhv = Xt + 512;
    for (int g2 = 0; g2 < 4; ++g2) {
      int node0 = blk * 16 + g2 * 4;
      __syncthreads();
#pragma unroll
      for (int u = 0; u < 2; ++u) {
        int idx = u * 256 + t;
        int nl = idx >> 7, c = idx & 127;
        int node = node0 + nl;
        cat[idx] = (c < 64) ? red[(g2 * 4 + nl) * 64 + c] + vnL[(node >> 9) * 64 + c]
                            : tmp[node * 64 + (c - 64)];
      }
      __syncthreads();
      int nl = t >> 6, h = t & 63;
      float acc = cb[l * 64 + h];
      const float* wp = cw + l * 8192 + h;
      for (int c = 0; c < 128; c += 4) {
        float4 xv = *(const float4*)&cat[nl * 128 + c];
        acc += xv.x * wp[c * 64] + xv.y * wp[(c + 1) * 64]
             + xv.z * wp[(c + 2) * 64] + xv.w * wp[(c + 3) * 64];
      }
      float v = tanh_fast(acc);
      int node = node0 + nl;
      alls16[node * 256 + (l + 1) * 64 + h] = f2bfs(v);
      if (do_gcn) {
        nhv[t] = v;
        __syncthreads();
        float g = 0.f;
        for (int c = 0; c < 64; ++c) g += nhv[nl * 64 + c] * gw_next[c * 64 + h];
        tmp[node * 64 + h] = g;
      }
    }
  }
}

// ---- latent MLP (8 nodes/block) + fused final head via last-block ------------
__global__ __launch_bounds__(256) void k_latfinal(const u16* __restrict__ alls16,
    const float* __restrict__ w1, const float* __restrict__ bb1,
    const float* __restrict__ w2, const float* __restrict__ bb2,
    float* __restrict__ latpart, int* cnt,
    const float* __restrict__ f1w, const float* __restrict__ f1b,
    const float* __restrict__ f2w, const float* __restrict__ f2b,
    float* __restrict__ outp) {
  __shared__ float x[8][256];
  __shared__ float t1[8][256];
  __shared__ float red[8][256];
  __shared__ int isLastL;
  int t = threadIdx.x;
  int b = blockIdx.x >> 6, chunk = blockIdx.x & 63;
#pragma unroll
  for (int u = 0; u < 8; ++u)
    x[u][t] = bfu(alls16[(size_t)(b * 512 + chunk * 8 + u) * 256 + t]);
  __syncthreads();
  float a1[8];
  float bb = bb1[t];
#pragma unroll
  for (int u = 0; u < 8; ++u) a1[u] = bb;
  for (int c = 0; c < 256; ++c) {
    float wv = w1[c * 256 + t];
#pragma unroll
    for (int u = 0; u < 8; ++u) a1[u] += x[u][c] * wv;
  }
#pragma unroll
  for (int u = 0; u < 8; ++u) t1[u][t] = tanh_fast(a1[u]);
  __syncthreads();
  int quar = t >> 6, k = t & 63, c0 = quar * 64;
  float a2[8];
#pragma unroll
  for (int u = 0; u < 8; ++u) a2[u] = 0.f;
  for (int c = 0; c < 64; ++c) {
    float wv = w2[(c0 + c) * 64 + k];
#pragma unroll
    for (int u = 0; u < 8; ++u) a2[u] += t1[u][c0 + c] * wv;
  }
#pragma unroll
  for (int u = 0; u < 8; ++u) red[u][t] = a2[u];
  __syncthreads();
  if (t < 64) {
    float acc2 = 0.f;
    float b2v = bb2[t];
#pragma unroll
    for (int u = 0; u < 8; ++u) {
      float s = red[u][t] + red[u][t + 64] + red[u][t + 128] + red[u][t + 192] + b2v;
      acc2 += tanh_fast(s);
    }
    latpart[(b * 64 + chunk) * 64 + t] = acc2;
  }
  __threadfence();
  __syncthreads();
  if (t == 0) isLastL = (atomicAdd(cnt, 1) == 255);
  __syncthreads();
  if (isLastL) {
    __threadfence();
    float* ls = &red[0][0];
    float* hb = &x[0][0];
    {
      int bb2_ = t >> 6, z = t & 63;
      float s = 0.f;
      for (int c = 0; c < 64; ++c) s += latpart[(bb2_ * 64 + c) * 64 + z];
      ls[t] = s;
      outp[4 + t] = s;  // lat_sum (fp32)
    }
    __syncthreads();
    for (int rep = 0; rep < 8; ++rep) {
      int idx = rep * 256 + t;
      int bb2_ = idx >> 9, kk = idx & 511;
      float acc = f1b[kk];
      for (int z = 0; z < 64; ++z) acc += ls[bb2_ * 64 + z] * f1w[z * 512 + kk];
      hb[idx] = tanh_fast(acc);
    }
    __syncthreads();
    {
      int bb2_ = t >> 6, lane = t & 63;
      float acc = 0.f;
#pragma unroll
      for (int u = 0; u < 8; ++u) acc += hb[bb2_ * 512 + lane + u * 64] * f2w[lane + u * 64];
#pragma unroll
      for (int off = 32; off > 0; off >>= 1) acc += __shfl_xor(acc, off, 64);
      if (lane == 0) outp[bb2_] = acc + f2b[0];  // predict (fp32)
    }
  }
}

extern "C" void kernel_launch(void* const* d_in, const int* in_sizes, int n_in,
                              void* d_out, int out_size, void* d_ws, size_t ws_size,
                              hipStream_t stream) {
  const float* adj       = (const float*)d_in[0];
  const float* node_feat = (const float*)d_in[1];
  const float* edge_feat = (const float*)d_in[2];
  const float* nf1_w = (const float*)d_in[3];
  const float* nf1_b = (const float*)d_in[4];
  const float* nf2_w = (const float*)d_in[5];
  const float* nf2_b = (const float*)d_in[6];
  const float* ef1_w = (const float*)d_in[7];
  const float* ef1_b = (const float*)d_in[8];
  const float* ef2_w = (const float*)d_in[9];
  const float* ef2_b = (const float*)d_in[10];
  const float* gcn_w = (const float*)d_in[11];
  const float* vn1_w = (const float*)d_in[12];
  const float* vn1_b = (const float*)d_in[13];
  const float* vn1_g = (const float*)d_in[14];
  const float* vn1_be = (const float*)d_in[15];
  const float* vn2_w = (const float*)d_in[16];
  const float* vn2_b = (const float*)d_in[17];
  const float* vn2_g = (const float*)d_in[18];
  const float* vn2_be = (const float*)d_in[19];
  const float* comb_w = (const float*)d_in[20];
  const float* comb_b = (const float*)d_in[21];
  const float* lat1_w = (const float*)d_in[22];
  const float* lat1_b = (const float*)d_in[23];
  const float* lat2_w = (const float*)d_in[24];
  const float* lat2_b = (const float*)d_in[25];
  const float* fc1_w = (const float*)d_in[26];
  const float* fc1_b = (const float*)d_in[27];
  const float* fc2_w = (const float*)d_in[28];
  const float* fc2_b = (const float*)d_in[29];

  const int use16 = (ws_size < (size_t)12 * 1024 * 1024) ? 1 : 0;
  char* p = (char*)d_ws;
  float* es32 = (float*)p;
  u16*   es16 = (u16*)p;
  size_t es_bytes = use16 ? (size_t)1048576 * 2 : (size_t)1048576 * 4;
  u16*   alls16  = (u16*)(p + es_bytes);      // 524288 u16
  float* hmid    = (float*)(alls16 + 524288); // 131072 f32
  float* tmp     = hmid + 131072;             // 131072
  float* dinv    = tmp + 131072;              // 2048
  float* vnpart  = dinv + 2048;               // 16384 (8192 used)
  float* vn_unused = vnpart + 16384;          // 256 (layout stability)
  float* latpart = vn_unused + 256;           // 16384
  int*   cnt     = (int*)(latpart + 16384);   // 16

  k_pre<<<512, 256, 0, stream>>>(node_feat, nf1_w, nf1_b, nf2_w, nf2_b,
                                 gcn_w, adj, alls16, tmp, dinv, cnt);
  k_edge<<<1024, 256, 0, stream>>>(edge_feat, ef1_w, ef1_b, ef2_w, ef2_b,
                                   es32, es16, use16);
  for (int l = 0; l < 3; ++l) {
    k_layer<<<128, 256, 0, stream>>>(adj, es32, es16, use16,
        hmid, tmp, vnpart, dinv, cnt + l,
        vn1_w, vn1_b, vn1_g, vn1_be, vn2_w, vn2_b, vn2_g, vn2_be,
        comb_w, comb_b, gcn_w + (l + 1) * 4096, alls16, l, (l < 2) ? 1 : 0);
  }
  k_latfinal<<<256, 256, 0, stream>>>(alls16, lat1_w, lat1_b, lat2_w, lat2_b,
                                      latpart, cnt + 3,
                                      fc1_w, fc1_b, fc2_w, fc2_b, (float*)d_out);
}

// Round 10
// 506.023 us; speedup vs baseline: 1.6998x; 1.4885x over previous
//
#include <hip/hip_runtime.h>
#include <math.h>

typedef unsigned short u16;
typedef unsigned int u32;

typedef __attribute__((ext_vector_type(8))) short short8;
typedef __attribute__((ext_vector_type(4))) float floatx4;

#define NTILES 16384  // B*N*N/64

__device__ __forceinline__ float bfu(u16 u) { return __uint_as_float(((u32)u) << 16); }
__device__ __forceinline__ u16 f2bfs(float f) {
  u32 x = __float_as_uint(f);
  return (u16)((x + 0x7FFFu + ((x >> 16) & 1u)) >> 16);
}
__device__ __forceinline__ float tanh_fast(float x) {
  float e = __builtin_amdgcn_exp2f(x * 2.885390081777927f);
  return 1.0f - 2.0f * __builtin_amdgcn_rcpf(e + 1.0f);
}

// ------ edge MLP -> e_sum: hi/lo-split MFMA layer-1, all weight frags in LDS --
// (hi/lo split numerics HW-proven in R8 [absmax 2.0]; this version fixes R8's
//  VGPR cliff by keeping W1/W2 fragments in LDS instead of 192 registers.)
__global__ __launch_bounds__(256) void k_edge(const float* __restrict__ ef,
    const float* __restrict__ w1, const float* __restrict__ b1,
    const float* __restrict__ w2, const float* __restrict__ b2,
    float* __restrict__ es32, u16* __restrict__ es16, int use16) {
  __shared__ __align__(16) short T1[64 * 264];   // layer-1 activations (bf16)
  __shared__ __align__(16) short W2L[64 * 264];  // W2^T bf16, n-major, +8 pad
  __shared__ __align__(16) short W1L[2 * 2056];  // W1 hi/lo frags, padded
  int t = threadIdx.x;
  int lane = t & 63, w = t >> 6, q = lane >> 4, r = lane & 15;

  // stage W2^T (bf16): W2L[n*264 + k]
  for (int u = 0; u < 64; ++u) {
    int flat = u * 256 + t;          // flat = k*64 + n
    int k = flat >> 6, n = flat & 63;
    W2L[n * 264 + k] = (short)f2bfs(w2[flat]);
  }
  // stage W1 hi/lo fragments: [hilo*2056 + (nt*16+r)*8 + j]
#pragma unroll
  for (int u = 0; u < 2; ++u) {
    int flat = u * 256 + t;
    int hilo = flat >> 8, idx = flat & 255;      // idx = nt*16 + r
    short8 v;
#pragma unroll
    for (int j = 0; j < 8; ++j) {
      float x = w1[j * 256 + idx];
      u32 xb = __float_as_uint(x);
      u16 hi = (u16)(xb >> 16);                  // truncated bf16 hi
      v[j] = hilo ? (short)f2bfs(x - bfu(hi)) : (short)hi;
    }
    *(short8*)&W1L[hilo * 2056 + idx * 8] = v;
  }
  float b1v[16];
#pragma unroll
  for (int nt = 0; nt < 16; ++nt) b1v[nt] = b1[nt * 16 + r];
  float b2v[4];
#pragma unroll
  for (int nt = 0; nt < 4; ++nt) b2v[nt] = b2[nt * 16 + r];
  __syncthreads();

  for (int tile = blockIdx.x; tile < NTILES; tile += gridDim.x) {
    // layer-1 A-frag straight from global: edge m = w*16+r, k-slot = q*8+j
    // slots q even: e_hi, q odd: e_lo  (B slots: q0/q1 w_hi, q2/q3 w_lo)
    const float4* ep = (const float4*)(ef + (size_t)tile * 512 + (size_t)(w * 16 + r) * 8);
    float4 e0 = ep[0], e1 = ep[1];
    float ev[8] = {e0.x, e0.y, e0.z, e0.w, e1.x, e1.y, e1.z, e1.w};
    short8 af1;
#pragma unroll
    for (int j = 0; j < 8; ++j) {
      u32 xb = __float_as_uint(ev[j]);
      u16 hi = (u16)(xb >> 16);
      af1[j] = (q & 1) ? (short)f2bfs(ev[j] - bfu(hi)) : (short)hi;
    }
    __syncthreads();   // prev tile's layer-2 T1 reads complete
    // layer 1: 16 MFMAs; (e_hi+e_lo)*(w_hi+w_lo) summed by K-slot layout
#pragma unroll
    for (int g = 0; g < 4; ++g) {
      floatx4 c1[4];
#pragma unroll
      for (int u = 0; u < 4; ++u) {
        float bb = b1v[g * 4 + u];
        c1[u] = (floatx4){bb, bb, bb, bb};
      }
#pragma unroll
      for (int u = 0; u < 4; ++u) {
        short8 bf = *(const short8*)&W1L[(q >> 1) * 2056 + ((g * 4 + u) * 16 + r) * 8];
        c1[u] = __builtin_amdgcn_mfma_f32_16x16x32_bf16(af1, bf, c1[u], 0, 0, 0);
      }
#pragma unroll
      for (int u = 0; u < 4; ++u)
#pragma unroll
        for (int reg = 0; reg < 4; ++reg)
          T1[(w * 16 + q * 4 + reg) * 264 + (g * 4 + u) * 16 + r] =
              (short)f2bfs(tanh_fast(c1[u][reg]));
    }
    __syncthreads();
    // layer 2 via MFMA; A from T1, B from W2L (R5-verified layout)
    floatx4 acc4[4];
#pragma unroll
    for (int nt = 0; nt < 4; ++nt) acc4[nt] = (floatx4){0.f, 0.f, 0.f, 0.f};
    const short* arow = &T1[(w * 16 + r) * 264];
#pragma unroll
    for (int s = 0; s < 8; ++s) {
      short8 af = *(const short8*)(arow + s * 32 + q * 8);
#pragma unroll
      for (int nt = 0; nt < 4; ++nt) {
        short8 bf = *(const short8*)&W2L[(nt * 16 + r) * 264 + s * 32 + q * 8];
        acc4[nt] = __builtin_amdgcn_mfma_f32_16x16x32_bf16(af, bf, acc4[nt], 0, 0, 0);
      }
    }
    float s0 = 0.f, s1 = 0.f, s2 = 0.f, s3 = 0.f;
#pragma unroll
    for (int nt = 0; nt < 4; ++nt) {
      float bb = b2v[nt];
      s0 += tanh_fast(acc4[nt][0] + bb);
      s1 += tanh_fast(acc4[nt][1] + bb);
      s2 += tanh_fast(acc4[nt][2] + bb);
      s3 += tanh_fast(acc4[nt][3] + bb);
    }
#pragma unroll
    for (int off = 1; off < 16; off <<= 1) {
      s0 += __shfl_xor(s0, off, 64);
      s1 += __shfl_xor(s1, off, 64);
      s2 += __shfl_xor(s2, off, 64);
      s3 += __shfl_xor(s3, off, 64);
    }
    if (r == 0) {
      int base = tile * 64 + w * 16 + q * 4;
      if (use16) {
        es16[base] = f2bfs(s0); es16[base + 1] = f2bfs(s1);
        es16[base + 2] = f2bfs(s2); es16[base + 3] = f2bfs(s3);
      } else {
        float4 o; o.x = s0; o.y = s1; o.z = s2; o.w = s3;
        *(float4*)&es32[base] = o;
      }
    }
  }
}

// ---- k_pre: node embed MLP + gcn_tmp(l=0) + dinv + counter zero --------------
__global__ __launch_bounds__(256) void k_pre(const float* __restrict__ nf,
    const float* __restrict__ w1, const float* __restrict__ b1,
    const float* __restrict__ w2, const float* __restrict__ b2,
    const float* __restrict__ gw, const float* __restrict__ adj,
    float* __restrict__ hid, u16* __restrict__ alls16, float* __restrict__ tmp,
    float* __restrict__ dinv, int* __restrict__ cnt) {
  __shared__ float nfx[4][16];
  __shared__ float t1[4][256];
  __shared__ float nh[4][64];
  int t = threadIdx.x;
  int node0 = blockIdx.x * 4;
  if (blockIdx.x == 0 && t < 16) cnt[t] = 0;
  if (t < 64) nfx[t >> 4][t & 15] = nf[node0 * 16 + t];
  __syncthreads();
  float b1t = b1[t];
  float a0 = b1t, a1 = b1t, a2 = b1t, a3 = b1t;
#pragma unroll
  for (int c = 0; c < 16; ++c) {
    float wv = w1[c * 256 + t];
    a0 += nfx[0][c] * wv; a1 += nfx[1][c] * wv;
    a2 += nfx[2][c] * wv; a3 += nfx[3][c] * wv;
  }
  t1[0][t] = tanh_fast(a0); t1[1][t] = tanh_fast(a1);
  t1[2][t] = tanh_fast(a2); t1[3][t] = tanh_fast(a3);
  __syncthreads();
  int nl = t >> 6, h = t & 63;
  {
    float acc = b2[h];
    for (int c = 0; c < 256; c += 4) {
      float4 xv = *(const float4*)&t1[nl][c];
      acc += xv.x * w2[c * 64 + h] + xv.y * w2[(c + 1) * 64 + h]
           + xv.z * w2[(c + 2) * 64 + h] + xv.w * w2[(c + 3) * 64 + h];
    }
    float v = tanh_fast(acc);
    int node = node0 + nl;
    hid[node * 64 + h] = v;
    alls16[node * 256 + h] = f2bfs(v);
    nh[nl][h] = v;
  }
  __syncthreads();
  {
    float g = 0.f;
    for (int c = 0; c < 64; ++c) g += nh[nl][c] * gw[c * 64 + h];
    tmp[(node0 + nl) * 64 + h] = g;
  }
  {
    int lane = t & 63, row = node0 + (t >> 6);
    float s = 0.f;
#pragma unroll
    for (int u = 0; u < 8; ++u) s += adj[(size_t)row * 512 + u * 64 + lane];
#pragma unroll
    for (int off = 32; off > 0; off >>= 1) s += __shfl_xor(s, off, 64);
    if (lane == 0) dinv[row] = 1.0f / (s + 1.0f);
  }
}

// ------- adjacency matmul (R5-proven): 8 rows/block, fp32 VALU ----------------
// MODE 0: A=adj, scale=dinv, X=tmp, out=hidden, + vn partials + last-block vn_mlp
// MODE 1: A=e_sum, X=hidden+vn, out=gated
template <int MODE>
__global__ __launch_bounds__(256) void k_adjmm(const float* __restrict__ adj,
    const float* __restrict__ es32, const u16* __restrict__ es16, int use16,
    const float* __restrict__ X, const float* __restrict__ vnin,
    const float* __restrict__ dinv,
    float* __restrict__ out, float* __restrict__ vnpart, int* cnt,
    const float* __restrict__ vw1, const float* __restrict__ vb1,
    const float* __restrict__ vg1, const float* __restrict__ vbe1,
    const float* __restrict__ vw2, const float* __restrict__ vb2,
    const float* __restrict__ vg2, const float* __restrict__ vbe2,
    float* __restrict__ vnout, int l) {
  __shared__ float Xt[64 * 64];
  __shared__ float Al[8 * 65];
  __shared__ floatx4 red4[256];
  __shared__ int isLast;
  int t = threadIdx.x;
  int b = blockIdx.x >> 6, it = blockIdx.x & 63;
  int hq = t & 15, slot = t >> 4, row = slot & 7, half = slot >> 3;
  floatx4 acc = (floatx4){0.f, 0.f, 0.f, 0.f};
  for (int jt = 0; jt < 8; ++jt) {
    __syncthreads();
    for (int u = 0; u < 16; ++u) {
      int idx = u * 256 + t;
      int jl = idx >> 6, hh = idx & 63;
      float xv = X[(b * 512 + jt * 64 + jl) * 64 + hh];
      if (MODE) xv += vnin[b * 64 + hh];
      Xt[idx] = xv;
    }
#pragma unroll
    for (int u = 0; u < 2; ++u) {
      int idx = u * 256 + t;
      int il = idx >> 6, jl = idx & 63;
      size_t ai = ((size_t)(b * 512 + it * 8 + il)) * 512 + jt * 64 + jl;
      float av;
      if (MODE) av = use16 ? bfu(es16[ai]) : es32[ai];
      else      av = adj[ai];
      Al[il * 65 + jl] = av;
    }
    __syncthreads();
    const float* xp = &Xt[(half * 32) * 64 + hq * 4];
    const float* ap = &Al[row * 65 + half * 32];
#pragma unroll
    for (int jl = 0; jl < 32; ++jl) {
      floatx4 xv = *(const floatx4*)(xp + jl * 64);
      float a = ap[jl];
      acc[0] += a * xv[0]; acc[1] += a * xv[1];
      acc[2] += a * xv[2]; acc[3] += a * xv[3];
    }
  }
  red4[t] = acc;
  __syncthreads();
  if (t < 128) {   // slot = row (half 0); pair at t+128 is half 1
    floatx4 s = red4[t], s2 = red4[t + 128];
    int gr = b * 512 + it * 8 + row;
    floatx4 o;
    if (MODE) {
#pragma unroll
      for (int i = 0; i < 4; ++i) o[i] = tanh_fast(s[i] + s2[i]);
    } else {
      float d = dinv[gr];
#pragma unroll
      for (int i = 0; i < 4; ++i) o[i] = tanh_fast((s[i] + s2[i]) * d);
    }
    *(floatx4*)&out[gr * 64 + hq * 4] = o;
    if (!MODE) red4[t] = o;
  }
  if (!MODE) {
    __syncthreads();
    if (t < 16) {
      floatx4 ssum = (floatx4){0.f, 0.f, 0.f, 0.f};
#pragma unroll
      for (int r2 = 0; r2 < 8; ++r2) {
        floatx4 v = red4[r2 * 16 + t];
        ssum[0] += v[0]; ssum[1] += v[1]; ssum[2] += v[2]; ssum[3] += v[3];
      }
      *(floatx4*)&vnpart[(b * 64 + it) * 64 + t * 4] = ssum;
    }
    __threadfence();
    __syncthreads();
    if (t == 0) isLast = (atomicAdd(cnt, 1) == 255);
    __syncthreads();
    if (isLast) {
      __threadfence();
      float* x0 = Xt; float* x1 = Xt + 256; float* y1 = Xt + 768; float* x2 = Xt + 1280;
      {
        int bb = t >> 6, h = t & 63;
        float s = 0.f;
        for (int c = 0; c < 64; ++c) s += vnpart[(bb * 64 + c) * 64 + h];
        x0[t] = s * (1.0f / 512.0f);
      }
      __syncthreads();
      for (int rep = 0; rep < 2; ++rep) {
        int idx = rep * 256 + t;
        int bb = idx >> 7, j = idx & 127;
        float a = vb1[l * 128 + j];
        for (int h = 0; h < 64; ++h) a += x0[bb * 64 + h] * vw1[l * 8192 + h * 128 + j];
        x1[idx] = a;
      }
      __syncthreads();
      if (t < 128) {
        int j = t;
        float a = x1[j], bq = x1[128 + j], c = x1[256 + j], d = x1[384 + j];
        float m = 0.25f * (a + bq + c + d);
        float da = a - m, db = bq - m, dc = c - m, dd = d - m;
        float var = 0.25f * (da * da + db * db + dc * dc + dd * dd);
        float sc = vg1[l * 128 + j] / sqrtf(var + 1e-5f);
        float be = vbe1[l * 128 + j];
        y1[j]       = fmaxf(sc * da + be, 0.f);
        y1[128 + j] = fmaxf(sc * db + be, 0.f);
        y1[256 + j] = fmaxf(sc * dc + be, 0.f);
        y1[384 + j] = fmaxf(sc * dd + be, 0.f);
      }
      __syncthreads();
      {
        int bb = t >> 6, k = t & 63;
        float a = vb2[l * 64 + k];
        for (int j = 0; j < 128; ++j) a += y1[bb * 128 + j] * vw2[l * 8192 + j * 64 + k];
        x2[t] = a;
      }
      __syncthreads();
      if (t < 64) {
        int k = t;
        float a = x2[k], bq = x2[64 + k], c = x2[128 + k], d = x2[192 + k];
        float m = 0.25f * (a + bq + c + d);
        float da = a - m, db = bq - m, dc = c - m, dd = d - m;
        float var = 0.25f * (da * da + db * db + dc * dc + dd * dd);
        float sc = vg2[l * 64 + k] / sqrtf(var + 1e-5f);
        float be = vbe2[l * 64 + k];
        vnout[k]       = fmaxf(sc * da + be, 0.f);
        vnout[64 + k]  = fmaxf(sc * db + be, 0.f);
        vnout[128 + k] = fmaxf(sc * dc + be, 0.f);
        vnout[192 + k] = fmaxf(sc * dd + be, 0.f);
      }
    }
  }
}

// -------- comb (+ fused gcn_tmp for next layer), 4 nodes/block (R5-proven) ----
__global__ __launch_bounds__(256) void k_comb_gcn(const float* hid,
    const float* gated, const float* __restrict__ vn,
    const float* __restrict__ cw, const float* __restrict__ cb,
    const float* __restrict__ gw_next,
    u16* __restrict__ alls16, float* tmpout, int l, int do_gcn) {
  __shared__ float cat[4 * 128];
  __shared__ float nh[4][64];
  int t = threadIdx.x;
  int node0 = blockIdx.x * 4;
#pragma unroll
  for (int u = 0; u < 2; ++u) {
    int idx = u * 256 + t;
    int nl = idx >> 7, c = idx & 127;
    int node = node0 + nl;
    int b = node >> 9;
    float v;
    if (c < 64) v = hid[node * 64 + c] + vn[b * 64 + c];
    else        v = gated[node * 64 + (c - 64)];
    cat[idx] = v;
  }
  __syncthreads();
  int nl = t >> 6, h = t & 63;
  float acc = cb[l * 64 + h];
  const float* wp = cw + l * 8192 + h;
  for (int c = 0; c < 128; c += 4) {
    float4 xv = *(const float4*)&cat[nl * 128 + c];
    acc += xv.x * wp[c * 64] + xv.y * wp[(c + 1) * 64]
         + xv.z * wp[(c + 2) * 64] + xv.w * wp[(c + 3) * 64];
  }
  float v = tanh_fast(acc);
  int node = node0 + nl;
  ((float*)hid)[node * 64 + h] = v;   // in-place update (block-local rows)
  alls16[node * 256 + (l + 1) * 64 + h] = f2bfs(v);
  if (do_gcn) {
    nh[nl][h] = v;
    __syncthreads();
    float g = 0.f;
    for (int c = 0; c < 64; ++c) g += nh[nl][c] * gw_next[c * 64 + h];
    tmpout[node * 64 + h] = g;
  }
}

// ---- latent MLP (8 nodes/block) + fused final head via last-block ------------
__global__ __launch_bounds__(256) void k_latfinal(const u16* __restrict__ alls16,
    const float* __restrict__ w1, const float* __restrict__ bb1,
    const float* __restrict__ w2, const float* __restrict__ bb2,
    float* __restrict__ latpart, int* cnt,
    const float* __restrict__ f1w, const float* __restrict__ f1b,
    const float* __restrict__ f2w, const float* __restrict__ f2b,
    float* __restrict__ outp) {
  __shared__ float x[8][256];
  __shared__ float t1[8][256];
  __shared__ float red[8][256];
  __shared__ int isLastL;
  int t = threadIdx.x;
  int b = blockIdx.x >> 6, chunk = blockIdx.x & 63;
#pragma unroll
  for (int u = 0; u < 8; ++u)
    x[u][t] = bfu(alls16[(size_t)(b * 512 + chunk * 8 + u) * 256 + t]);
  __syncthreads();
  float a1[8];
  float bb = bb1[t];
#pragma unroll
  for (int u = 0; u < 8; ++u) a1[u] = bb;
  for (int c = 0; c < 256; ++c) {
    float wv = w1[c * 256 + t];
#pragma unroll
    for (int u = 0; u < 8; ++u) a1[u] += x[u][c] * wv;
  }
#pragma unroll
  for (int u = 0; u < 8; ++u) t1[u][t] = tanh_fast(a1[u]);
  __syncthreads();
  int quar = t >> 6, k = t & 63, c0 = quar * 64;
  float a2[8];
#pragma unroll
  for (int u = 0; u < 8; ++u) a2[u] = 0.f;
  for (int c = 0; c < 64; ++c) {
    float wv = w2[(c0 + c) * 64 + k];
#pragma unroll
    for (int u = 0; u < 8; ++u) a2[u] += t1[u][c0 + c] * wv;
  }
#pragma unroll
  for (int u = 0; u < 8; ++u) red[u][t] = a2[u];
  __syncthreads();
  if (t < 64) {
    float acc2 = 0.f;
    float b2v = bb2[t];
#pragma unroll
    for (int u = 0; u < 8; ++u) {
      float s = red[u][t] + red[u][t + 64] + red[u][t + 128] + red[u][t + 192] + b2v;
      acc2 += tanh_fast(s);
    }
    latpart[(b * 64 + chunk) * 64 + t] = acc2;
  }
  __threadfence();
  __syncthreads();
  if (t == 0) isLastL = (atomicAdd(cnt, 1) == 255);
  __syncthreads();
  if (isLastL) {
    __threadfence();
    float* ls = &red[0][0];
    float* hb = &x[0][0];
    {
      int bb2_ = t >> 6, z = t & 63;
      float s = 0.f;
      for (int c = 0; c < 64; ++c) s += latpart[(bb2_ * 64 + c) * 64 + z];
      ls[t] = s;
      outp[4 + t] = s;  // lat_sum (fp32)
    }
    __syncthreads();
    for (int rep = 0; rep < 8; ++rep) {
      int idx = rep * 256 + t;
      int bb2_ = idx >> 9, kk = idx & 511;
      float acc = f1b[kk];
      for (int z = 0; z < 64; ++z) acc += ls[bb2_ * 64 + z] * f1w[z * 512 + kk];
      hb[idx] = tanh_fast(acc);
    }
    __syncthreads();
    {
      int bb2_ = t >> 6, lane = t & 63;
      float acc = 0.f;
#pragma unroll
      for (int u = 0; u < 8; ++u) acc += hb[bb2_ * 512 + lane + u * 64] * f2w[lane + u * 64];
#pragma unroll
      for (int off = 32; off > 0; off >>= 1) acc += __shfl_xor(acc, off, 64);
      if (lane == 0) outp[bb2_] = acc + f2b[0];  // predict (fp32)
    }
  }
}

extern "C" void kernel_launch(void* const* d_in, const int* in_sizes, int n_in,
                              void* d_out, int out_size, void* d_ws, size_t ws_size,
                              hipStream_t stream) {
  const float* adj       = (const float*)d_in[0];
  const float* node_feat = (const float*)d_in[1];
  const float* edge_feat = (const float*)d_in[2];
  const float* nf1_w = (const float*)d_in[3];
  const float* nf1_b = (const float*)d_in[4];
  const float* nf2_w = (const float*)d_in[5];
  const float* nf2_b = (const float*)d_in[6];
  const float* ef1_w = (const float*)d_in[7];
  const float* ef1_b = (const float*)d_in[8];
  const float* ef2_w = (const float*)d_in[9];
  const float* ef2_b = (const float*)d_in[10];
  const float* gcn_w = (const float*)d_in[11];
  const float* vn1_w = (const float*)d_in[12];
  const float* vn1_b = (const float*)d_in[13];
  const float* vn1_g = (const float*)d_in[14];
  const float* vn1_be = (const float*)d_in[15];
  const float* vn2_w = (const float*)d_in[16];
  const float* vn2_b = (const float*)d_in[17];
  const float* vn2_g = (const float*)d_in[18];
  const float* vn2_be = (const float*)d_in[19];
  const float* comb_w = (const float*)d_in[20];
  const float* comb_b = (const float*)d_in[21];
  const float* lat1_w = (const float*)d_in[22];
  const float* lat1_b = (const float*)d_in[23];
  const float* lat2_w = (const float*)d_in[24];
  const float* lat2_b = (const float*)d_in[25];
  const float* fc1_w = (const float*)d_in[26];
  const float* fc1_b = (const float*)d_in[27];
  const float* fc2_w = (const float*)d_in[28];
  const float* fc2_b = (const float*)d_in[29];

  const int use16 = (ws_size < (size_t)12 * 1024 * 1024) ? 1 : 0;
  char* p = (char*)d_ws;
  float* es32 = (float*)p;
  u16*   es16 = (u16*)p;
  size_t es_bytes = use16 ? (size_t)1048576 * 2 : (size_t)1048576 * 4;
  u16*   alls16  = (u16*)(p + es_bytes);      // 524288 u16
  float* hid     = (float*)(alls16 + 524288); // 131072 f32
  float* tmp     = hid + 131072;              // 131072 (gcn tmp, then gated)
  float* dinv    = tmp + 131072;              // 2048
  float* vnpart  = dinv + 2048;               // 16384
  float* vn      = vnpart + 16384;            // 256
  float* latpart = vn + 256;                  // 16384
  int*   cnt     = (int*)(latpart + 16384);   // 16

  k_pre<<<512, 256, 0, stream>>>(node_feat, nf1_w, nf1_b, nf2_w, nf2_b,
                                 gcn_w, adj, hid, alls16, tmp, dinv, cnt);
  k_edge<<<1024, 256, 0, stream>>>(edge_feat, ef1_w, ef1_b, ef2_w, ef2_b,
                                   es32, es16, use16);
  for (int l = 0; l < 3; ++l) {
    k_adjmm<0><<<256, 256, 0, stream>>>(adj, es32, es16, use16, tmp, vn, dinv,
        hid, vnpart, cnt + l,
        vn1_w, vn1_b, vn1_g, vn1_be, vn2_w, vn2_b, vn2_g, vn2_be, vn, l);
    k_adjmm<1><<<256, 256, 0, stream>>>(adj, es32, es16, use16, hid, vn, dinv,
        tmp, vnpart, cnt + l,
        vn1_w, vn1_b, vn1_g, vn1_be, vn2_w, vn2_b, vn2_g, vn2_be, vn, l);
    k_comb_gcn<<<512, 256, 0, stream>>>(hid, tmp, vn, comb_w, comb_b,
        gcn_w + (l + 1) * 4096, alls16, tmp, l, (l < 2) ? 1 : 0);
  }
  k_latfinal<<<256, 256, 0, stream>>>(alls16, lat1_w, lat1_b, lat2_w, lat2_b,
                                      latpart, cnt + 3,
                                      fc1_w, fc1_b, fc2_w, fc2_b, (float*)d_out);
}